// Round 1
// baseline (1714.042 us; speedup 1.0000x reference)
//
#include <hip/hip_runtime.h>
#include <cstdint>

// ---- static config ----
constexpr int B = 8, P = 8, N = 100, D = 256, H = 8, DK = 32, M = 64, KG = 16;
constexpr int L = P * N;      // 800
constexpr int PATCH = 8;
constexpr int NN = N * N;     // 10000
constexpr float PHI_SCALE = 0.8408964152537145f;  // (1/sqrt(0.25)) * 32^-0.25
constexpr float MINV = 0.125f;                    // 64^-0.5

__device__ __forceinline__ unsigned fkey(float x) {
    unsigned u = __float_as_uint(x);
    return (u & 0x80000000u) ? ~u : (u | 0x80000000u);
}
__device__ __forceinline__ float fkey_inv(unsigned k) {
    return (k & 0x80000000u) ? __uint_as_float(k ^ 0x80000000u) : __uint_as_float(~k);
}

// ---- 1. q,k,v = xt @ W^T + b (three at once) ----
__global__ __launch_bounds__(256) void qkv_kernel(
    const float* __restrict__ x,
    const float* __restrict__ Wq, const float* __restrict__ bq,
    const float* __restrict__ Wk, const float* __restrict__ bk,
    const float* __restrict__ Wv, const float* __restrict__ bv,
    float* __restrict__ q, float* __restrict__ k, float* __restrict__ v)
{
    __shared__ float xs[8][256];
    const int row0 = blockIdx.x * 8;
    const int t = threadIdx.x;
    for (int r = 0; r < 8; ++r) xs[r][t] = x[(row0 + r) * 256 + t];
    __syncthreads();
    float aq[8], ak[8], av[8];
    #pragma unroll
    for (int r = 0; r < 8; ++r) { aq[r] = 0.f; ak[r] = 0.f; av[r] = 0.f; }
    const float* wq = Wq + t * 256;
    const float* wk = Wk + t * 256;
    const float* wv = Wv + t * 256;
    for (int kk = 0; kk < 256; ++kk) {
        float wqv = wq[kk], wkv = wk[kk], wvv = wv[kk];
        #pragma unroll
        for (int r = 0; r < 8; ++r) {
            float xv = xs[r][kk];
            aq[r] += xv * wqv; ak[r] += xv * wkv; av[r] += xv * wvv;
        }
    }
    float bqv = bq[t], bkv = bk[t], bvv = bv[t];
    for (int r = 0; r < 8; ++r) {
        q[(row0 + r) * 256 + t] = aq[r] + bqv;
        k[(row0 + r) * 256 + t] = ak[r] + bkv;
        v[(row0 + r) * 256 + t] = av[r] + bvv;
    }
}

// ---- 2a. phi(q): one 64-lane group per (b,l,h), lane = m ----
__global__ __launch_bounds__(256) void phi_q_kernel(
    const float* __restrict__ qb, const float* __restrict__ proj,
    float* __restrict__ qp)
{
    __shared__ float ps[64 * 33];
    const int t = threadIdx.x;
    for (int j = t; j < 2048; j += 256) ps[(j >> 5) * 33 + (j & 31)] = proj[j];
    __syncthreads();
    const int group = blockIdx.x * 4 + (t >> 6);
    const int m = t & 63;
    const int row = group >> 3;
    const int h = group & 7;
    const float* qptr = qb + row * 256 + h * 32;
    float dd = 0.f, diag = 0.f;
    #pragma unroll
    for (int d = 0; d < 32; ++d) {
        float qv = qptr[d] * PHI_SCALE;
        dd += qv * ps[m * 33 + d];
        diag += qv * qv;
    }
    diag *= 0.5f;
    float s = dd;
    #pragma unroll
    for (int off = 1; off < 64; off <<= 1) s = fmaxf(s, __shfl_xor(s, off));
    qp[group * 64 + m] = MINV * (expf(dd - diag - s) + 1e-6f);
}

// ---- 2b. phi(k) pass 1: store raw dd + diag, atomic per-(b,h) max ----
__global__ __launch_bounds__(256) void phi_k1_kernel(
    const float* __restrict__ kb, const float* __restrict__ proj,
    float* __restrict__ ddout, float* __restrict__ diagout,
    unsigned* __restrict__ kmaxkey)
{
    __shared__ float ps[64 * 33];
    const int t = threadIdx.x;
    for (int j = t; j < 2048; j += 256) ps[(j >> 5) * 33 + (j & 31)] = proj[j];
    __syncthreads();
    const int group = blockIdx.x * 4 + (t >> 6);
    const int m = t & 63;
    const int row = group >> 3;
    const int h = group & 7;
    const float* kptr = kb + row * 256 + h * 32;
    float dd = 0.f, diag = 0.f;
    #pragma unroll
    for (int d = 0; d < 32; ++d) {
        float kv = kptr[d] * PHI_SCALE;
        dd += kv * ps[m * 33 + d];
        diag += kv * kv;
    }
    diag *= 0.5f;
    ddout[group * 64 + m] = dd;
    float s = dd;
    #pragma unroll
    for (int off = 1; off < 64; off <<= 1) s = fmaxf(s, __shfl_xor(s, off));
    if (m == 0) {
        diagout[group] = diag;
        int b = row / L;
        atomicMax(&kmaxkey[b * 8 + h], fkey(s));
    }
}

// ---- 2c. phi(k) pass 2: elementwise finish ----
__global__ __launch_bounds__(256) void phi_k2_kernel(
    float* __restrict__ ddkp, const float* __restrict__ diagk,
    const unsigned* __restrict__ kmaxkey)
{
    const int idx = blockIdx.x * 256 + threadIdx.x;
    if (idx >= B * L * H * M) return;
    const int group = idx >> 6;
    const int h = group & 7;
    const int b = group / (L * H);
    float stab = fkey_inv(kmaxkey[b * 8 + h]);
    float dd = ddkp[idx];
    ddkp[idx] = MINV * (expf(dd - diagk[group] - stab) + 1e-6f);
}

// ---- 3. kvs[b,h,k,m,d] = sum_l kp*eg*v ; ksum = sum_l kp*eg ----
__global__ __launch_bounds__(256) void kvs_kernel(
    const float* __restrict__ kp, const float* __restrict__ vb,
    const float* __restrict__ gum, float* __restrict__ kvs,
    float* __restrict__ ksum)
{
    constexpr int TL = 16;
    __shared__ float kps[TL][64];
    __shared__ float vs[TL][32];
    __shared__ float egs[TL];
    const int bi = blockIdx.x;
    const int b = bi >> 7;            // /(H*KG)
    const int h = (bi >> 4) & 7;
    const int kk = bi & 15;
    const int t = threadIdx.x;
    const int d = t & 31;
    const int mb = (t >> 5) * 8;
    float acc[8] = {0, 0, 0, 0, 0, 0, 0, 0};
    float sacc[8] = {0, 0, 0, 0, 0, 0, 0, 0};
    for (int l0 = 0; l0 < L; l0 += TL) {
        for (int j = t; j < TL * 64; j += 256) {
            int ll = j >> 6, m = j & 63;
            kps[ll][m] = kp[((b * L + l0 + ll) * H + h) * 64 + m];
        }
        for (int j = t; j < TL * 32; j += 256) {
            int ll = j >> 5, d2 = j & 31;
            vs[ll][d2] = vb[(b * L + l0 + ll) * 256 + h * 32 + d2];
        }
        if (t < TL) egs[t] = expf(gum[((b * L + l0 + t) * H + h) * 16 + kk]);
        __syncthreads();
        for (int ll = 0; ll < TL; ++ll) {
            float ev = egs[ll];
            float tmp = ev * vs[ll][d];
            #pragma unroll
            for (int mi = 0; mi < 8; ++mi)
                acc[mi] += kps[ll][mb + mi] * tmp;
            if (d == 0) {
                #pragma unroll
                for (int mi = 0; mi < 8; ++mi)
                    sacc[mi] += kps[ll][mb + mi] * ev;
            }
        }
        __syncthreads();
    }
    const long base = ((long)(b * 8 + h) * 16 + kk) * 2048;
    for (int mi = 0; mi < 8; ++mi)
        kvs[base + (mb + mi) * 32 + d] = acc[mi];
    if (d == 0) {
        const long sb = ((long)(b * 8 + h) * 16 + kk) * 64;
        for (int mi = 0; mi < 8; ++mi) ksum[sb + mb + mi] = sacc[mi];
    }
}

// ---- 4. den[b,l,h,k] = qp . ksum + 1e-8 ----
__global__ __launch_bounds__(128) void den_kernel(
    const float* __restrict__ qp, const float* __restrict__ ksum,
    float* __restrict__ den)
{
    const int row = blockIdx.x;       // b*L + l
    const int t = threadIdx.x;        // 128
    const int h = t >> 4, kk = t & 15;
    const int b = row / L;
    const float* qpr = qp + (row * 8 + h) * 64;
    const float* ksr = ksum + ((b * 8 + h) * 16 + kk) * 64;
    float s = 0.f;
    #pragma unroll 8
    for (int m = 0; m < 64; ++m) s += qpr[m] * ksr[m];
    den[(row * 8 + h) * 16 + kk] = s + 1e-8f;
}

// ---- 5. z = LN(mean_k (qp.kvs)/den) ----
__global__ __launch_bounds__(256) void z_kernel(
    const float* __restrict__ qp, const float* __restrict__ kvs,
    const float* __restrict__ den, const float* __restrict__ ln_g,
    const float* __restrict__ ln_b, float* __restrict__ z)
{
    __shared__ float qps[80 * 64];
    __shared__ float kvss[2048];
    __shared__ float dens[80 * 16];
    const int bi = blockIdx.x;        // B*H*10
    const int b = bi / 80;
    const int h = (bi / 10) & 7;
    const int l0 = (bi % 10) * 80;
    const int t = threadIdx.x;
    const int d = t & 31, lr = t >> 5;
    for (int j = t; j < 80 * 64; j += 256) {
        int ll = j >> 6, m = j & 63;
        qps[j] = qp[((b * L + l0 + ll) * 8 + h) * 64 + m];
    }
    for (int j = t; j < 80 * 16; j += 256) {
        int ll = j >> 4, kk2 = j & 15;
        dens[j] = den[((b * L + l0 + ll) * 8 + h) * 16 + kk2];
    }
    float acc[10];
    #pragma unroll
    for (int i = 0; i < 10; ++i) acc[i] = 0.f;
    for (int kk = 0; kk < 16; ++kk) {
        __syncthreads();
        const float* kbase = kvs + ((long)(b * 8 + h) * 16 + kk) * 2048;
        for (int j = t; j < 2048; j += 256) kvss[j] = kbase[j];
        __syncthreads();
        #pragma unroll
        for (int li = 0; li < 10; ++li) {
            int ll = li * 8 + lr;
            float num = 0.f;
            #pragma unroll
            for (int m = 0; m < 64; ++m)
                num += qps[ll * 64 + m] * kvss[m * 32 + d];
            acc[li] += num / dens[ll * 16 + kk];
        }
    }
    float gg = ln_g[d], bb = ln_b[d];
    for (int li = 0; li < 10; ++li) {
        float zv = acc[li] * (1.0f / 16.0f);
        float s1 = zv, s2 = zv * zv;
        #pragma unroll
        for (int off = 1; off < 32; off <<= 1) {
            s1 += __shfl_xor(s1, off);
            s2 += __shfl_xor(s2, off);
        }
        float mu = s1 * (1.0f / 32.0f);
        float var = s2 * (1.0f / 32.0f) - mu * mu;
        float zn = (zv - mu) * rsqrtf(var + 1e-5f) * gg + bb;
        z[(b * L + l0 + li * 8 + lr) * 256 + h * 32 + d] = zn;
    }
}

// ---- 6. h1 = relu(flat @ fc_w^T + fc_b) ----
__global__ __launch_bounds__(256) void adjfc_kernel(
    const float* __restrict__ adj, const float* __restrict__ fcw,
    const float* __restrict__ fcb, float* __restrict__ h1)
{
    __shared__ float as[8][256];
    const int bp = blockIdx.x;
    const int b = bp >> 3, p = bp & 7;
    const int t = threadIdx.x;
    const int c = t & 127, ph = t >> 7;
    float acc[4] = {0, 0, 0, 0};
    const float* fw = fcw + (long)c * NN;
    for (int c0 = 0; c0 < NN; c0 += 256) {
        for (int j = t; j < 2048; j += 256) {
            int rr = j >> 8, cc = j & 255;
            int src = c0 + cc;
            as[rr][cc] = (src < NN) ? adj[((long)(b * 64 + p * 8 + rr)) * NN + src] : 0.f;
        }
        __syncthreads();
        int n = min(256, NN - c0);
        for (int cc = 0; cc < n; ++cc) {
            float wv = fw[c0 + cc];
            #pragma unroll
            for (int r4 = 0; r4 < 4; ++r4)
                acc[r4] += as[ph + r4 * 2][cc] * wv;
        }
        __syncthreads();
    }
    float bb = fcb[c];
    for (int r4 = 0; r4 < 4; ++r4) {
        int pl = ph + r4 * 2;
        h1[(bp * 8 + pl) * 128 + c] = fmaxf(acc[r4] + bb, 0.f);
    }
}

// ---- 7. w = softmax over patch_len of (h1 @ out_w^T + out_b) ----
__global__ __launch_bounds__(128) void wsm_kernel(
    const float* __restrict__ h1, const float* __restrict__ ow,
    const float* __restrict__ ob, float* __restrict__ wsm)
{
    __shared__ float part[8][2];
    const int bp = blockIdx.x;
    const int t = threadIdx.x;   // 128
    float owv = ow[t];
    for (int pl = 0; pl < 8; ++pl) {
        float v = h1[(bp * 8 + pl) * 128 + t] * owv;
        #pragma unroll
        for (int off = 1; off < 64; off <<= 1) v += __shfl_xor(v, off);
        if ((t & 63) == 0) part[pl][t >> 6] = v;
    }
    __syncthreads();
    if (t == 0) {
        float lg[8], mx = -1e30f;
        for (int pl = 0; pl < 8; ++pl) {
            lg[pl] = part[pl][0] + part[pl][1] + ob[0];
            mx = fmaxf(mx, lg[pl]);
        }
        float s = 0.f;
        for (int pl = 0; pl < 8; ++pl) { lg[pl] = expf(lg[pl] - mx); s += lg[pl]; }
        for (int pl = 0; pl < 8; ++pl) wsm[bp * 8 + pl] = lg[pl] / s;
    }
}

// ---- 8. fused + row L1-normalize ----
__global__ __launch_bounds__(128) void fused_kernel(
    const float* __restrict__ adj, const float* __restrict__ wsm,
    float* __restrict__ fusedn)
{
    __shared__ float part[2];
    const int bi = blockIdx.x;        // (b*8+p)*100 + i
    const int b = bi / 800;
    const int p = (bi / 100) & 7;
    const int i = bi % 100;
    const int t = threadIdx.x;        // 128
    float f = 0.f;
    if (t < 100) {
        #pragma unroll
        for (int pl = 0; pl < 8; ++pl)
            f += adj[((long)(b * 64 + p * 8 + pl)) * NN + i * 100 + t] * wsm[(b * 8 + p) * 8 + pl];
    }
    float a = fabsf(f);
    #pragma unroll
    for (int off = 1; off < 64; off <<= 1) a += __shfl_xor(a, off);
    if ((t & 63) == 0) part[t >> 6] = a;
    __syncthreads();
    float denom = fmaxf(part[0] + part[1], 1e-12f);
    if (t < 100) fusedn[(long)bi * 100 + t] = f / denom;
}

// ---- 9. z += block-diag(fusedn) @ v ----
__global__ __launch_bounds__(256) void bias_kernel(
    const float* __restrict__ fusedn, const float* __restrict__ vb,
    float* __restrict__ z)
{
    __shared__ float fs[10000];
    const int b = blockIdx.x >> 3, p = blockIdx.x & 7;
    const int t = threadIdx.x;
    for (int j = t; j < 10000; j += 256) fs[j] = fusedn[(long)(b * 8 + p) * 10000 + j];
    __syncthreads();
    const int col = t;
    for (int i0 = 0; i0 < 100; i0 += 10) {
        float acc[10];
        #pragma unroll
        for (int r = 0; r < 10; ++r) acc[r] = 0.f;
        for (int j = 0; j < 100; ++j) {
            float vj = vb[(b * 800 + p * 100 + j) * 256 + col];
            #pragma unroll
            for (int r = 0; r < 10; ++r)
                acc[r] += fs[(i0 + r) * 100 + j] * vj;
        }
        for (int r = 0; r < 10; ++r)
            z[(b * 800 + p * 100 + i0 + r) * 256 + col] += acc[r];
    }
}

// ---- 10. out = zb @ Wo^T + bo ----
__global__ __launch_bounds__(256) void out_kernel(
    const float* __restrict__ z, const float* __restrict__ Wo,
    const float* __restrict__ bo, float* __restrict__ out)
{
    __shared__ float zs[8][256];
    const int row0 = blockIdx.x * 8;
    const int t = threadIdx.x;
    for (int r = 0; r < 8; ++r) zs[r][t] = z[(row0 + r) * 256 + t];
    __syncthreads();
    float acc[8];
    #pragma unroll
    for (int r = 0; r < 8; ++r) acc[r] = 0.f;
    const float* w = Wo + t * 256;
    for (int kk = 0; kk < 256; ++kk) {
        float wv = w[kk];
        #pragma unroll
        for (int r = 0; r < 8; ++r) acc[r] += zs[r][kk] * wv;
    }
    float bb = bo[t];
    for (int r = 0; r < 8; ++r) out[(row0 + r) * 256 + t] = acc[r] + bb;
}

extern "C" void kernel_launch(void* const* d_in, const int* in_sizes, int n_in,
                              void* d_out, int out_size, void* d_ws, size_t ws_size,
                              hipStream_t stream) {
    const float* x     = (const float*)d_in[0];
    const float* adj   = (const float*)d_in[1];
    const float* Wq_w  = (const float*)d_in[2];
    const float* Wq_b  = (const float*)d_in[3];
    const float* Wk_w  = (const float*)d_in[4];
    const float* Wk_b  = (const float*)d_in[5];
    const float* Wv_w  = (const float*)d_in[6];
    const float* Wv_b  = (const float*)d_in[7];
    const float* Wo_w  = (const float*)d_in[8];
    const float* Wo_b  = (const float*)d_in[9];
    const float* ln_g  = (const float*)d_in[10];
    const float* ln_b  = (const float*)d_in[11];
    const float* fc_w  = (const float*)d_in[12];
    const float* fc_b  = (const float*)d_in[13];
    const float* out_w = (const float*)d_in[14];
    const float* out_b = (const float*)d_in[15];
    const float* proj  = (const float*)d_in[16];
    const float* gum   = (const float*)d_in[17];
    float* out = (float*)d_out;

    // workspace layout (floats)
    float* ws = (float*)d_ws;
    size_t off = 0;
    float* qbuf   = ws + off; off += (size_t)B * L * 256;      // 1,638,400
    float* kbuf   = ws + off; off += (size_t)B * L * 256;
    float* vbuf   = ws + off; off += (size_t)B * L * 256;
    float* qp     = ws + off; off += (size_t)B * L * H * M;    // 3,276,800
    float* kp     = ws + off; off += (size_t)B * L * H * M;
    float* diagk  = ws + off; off += (size_t)B * L * H;        // 51,200
    float* kvs    = ws + off; off += (size_t)B * H * KG * M * DK; // 2,097,152
    float* ksum   = ws + off; off += (size_t)B * H * KG * M;   // 65,536
    float* den    = ws + off; off += (size_t)B * L * H * KG;   // 819,200
    float* zbuf   = ws + off; off += (size_t)B * L * 256;      // 1,638,400
    float* h1     = ws + off; off += (size_t)64 * 8 * 128;     // 65,536
    float* wsm    = ws + off; off += 512;
    float* fusedn = ws + off; off += (size_t)64 * NN;          // 640,000
    unsigned* kmaxkey = (unsigned*)(ws + off); off += 64;

    hipMemsetAsync(kmaxkey, 0, 64 * sizeof(unsigned), stream);

    qkv_kernel<<<800, 256, 0, stream>>>(x, Wq_w, Wq_b, Wk_w, Wk_b, Wv_w, Wv_b,
                                        qbuf, kbuf, vbuf);
    phi_q_kernel<<<12800, 256, 0, stream>>>(qbuf, proj, qp);
    phi_k1_kernel<<<12800, 256, 0, stream>>>(kbuf, proj, kp, diagk, kmaxkey);
    phi_k2_kernel<<<12800, 256, 0, stream>>>(kp, diagk, kmaxkey);
    kvs_kernel<<<1024, 256, 0, stream>>>(kp, vbuf, gum, kvs, ksum);
    den_kernel<<<6400, 128, 0, stream>>>(qp, ksum, den);
    z_kernel<<<640, 256, 0, stream>>>(qp, kvs, den, ln_g, ln_b, zbuf);
    adjfc_kernel<<<64, 256, 0, stream>>>(adj, fc_w, fc_b, h1);
    wsm_kernel<<<64, 128, 0, stream>>>(h1, out_w, out_b, wsm);
    fused_kernel<<<6400, 128, 0, stream>>>(adj, wsm, fusedn);
    bias_kernel<<<64, 256, 0, stream>>>(fusedn, vbuf, zbuf);
    out_kernel<<<800, 256, 0, stream>>>(zbuf, Wo_w, Wo_b, out);
}

// Round 2
// 1433.775 us; speedup vs baseline: 1.1955x; 1.1955x over previous
//
#include <hip/hip_runtime.h>
#include <cstdint>

// ---- static config ----
constexpr int B = 8, P = 8, N = 100, D = 256, H = 8, DK = 32, M = 64, KG = 16;
constexpr int L = P * N;      // 800
constexpr int PATCH = 8;
constexpr int NN = N * N;     // 10000
constexpr float PHI_SCALE = 0.8408964152537145f;  // (1/sqrt(0.25)) * 32^-0.25
constexpr float MINV = 0.125f;                    // 64^-0.5
constexpr int ADJ_SPLIT = 20;                     // split-K for adjfc GEMM
constexpr int ADJ_KC = 512;                       // K-chunk (last = 272)

__device__ __forceinline__ unsigned fkey(float x) {
    unsigned u = __float_as_uint(x);
    return (u & 0x80000000u) ? ~u : (u | 0x80000000u);
}
__device__ __forceinline__ float fkey_inv(unsigned k) {
    return (k & 0x80000000u) ? __uint_as_float(k ^ 0x80000000u) : __uint_as_float(~k);
}

// ---- 1. q,k,v = xt @ W^T + b (three at once, float4 weight loads) ----
__global__ __launch_bounds__(256) void qkv_kernel(
    const float* __restrict__ x,
    const float* __restrict__ Wq, const float* __restrict__ bq,
    const float* __restrict__ Wk, const float* __restrict__ bk,
    const float* __restrict__ Wv, const float* __restrict__ bv,
    float* __restrict__ q, float* __restrict__ k, float* __restrict__ v)
{
    __shared__ float xs[8][256];
    const int row0 = blockIdx.x * 8;
    const int t = threadIdx.x;
    for (int r = 0; r < 8; ++r) xs[r][t] = x[(row0 + r) * 256 + t];
    __syncthreads();
    float aq[8], ak[8], av[8];
    #pragma unroll
    for (int r = 0; r < 8; ++r) { aq[r] = 0.f; ak[r] = 0.f; av[r] = 0.f; }
    const float4* wq4 = reinterpret_cast<const float4*>(Wq) + t * 64;
    const float4* wk4 = reinterpret_cast<const float4*>(Wk) + t * 64;
    const float4* wv4 = reinterpret_cast<const float4*>(Wv) + t * 64;
    for (int kk = 0; kk < 64; ++kk) {
        float4 wqv = wq4[kk], wkv = wk4[kk], wvv = wv4[kk];
        #pragma unroll
        for (int r = 0; r < 8; ++r) {
            const float* xr = &xs[r][kk * 4];
            aq[r] += xr[0] * wqv.x + xr[1] * wqv.y + xr[2] * wqv.z + xr[3] * wqv.w;
            ak[r] += xr[0] * wkv.x + xr[1] * wkv.y + xr[2] * wkv.z + xr[3] * wkv.w;
            av[r] += xr[0] * wvv.x + xr[1] * wvv.y + xr[2] * wvv.z + xr[3] * wvv.w;
        }
    }
    float bqv = bq[t], bkv = bk[t], bvv = bv[t];
    for (int r = 0; r < 8; ++r) {
        q[(row0 + r) * 256 + t] = aq[r] + bqv;
        k[(row0 + r) * 256 + t] = ak[r] + bkv;
        v[(row0 + r) * 256 + t] = av[r] + bvv;
    }
}

// ---- 2a. phi(q): one 64-lane group per (b,l,h), lane = m ----
__global__ __launch_bounds__(256) void phi_q_kernel(
    const float* __restrict__ qb, const float* __restrict__ proj,
    float* __restrict__ qp)
{
    __shared__ float ps[64 * 33];
    const int t = threadIdx.x;
    for (int j = t; j < 2048; j += 256) ps[(j >> 5) * 33 + (j & 31)] = proj[j];
    __syncthreads();
    const int group = blockIdx.x * 4 + (t >> 6);
    const int m = t & 63;
    const int row = group >> 3;
    const int h = group & 7;
    const float* qptr = qb + row * 256 + h * 32;
    float dd = 0.f, diag = 0.f;
    #pragma unroll
    for (int d = 0; d < 32; ++d) {
        float qv = qptr[d] * PHI_SCALE;
        dd += qv * ps[m * 33 + d];
        diag += qv * qv;
    }
    diag *= 0.5f;
    float s = dd;
    #pragma unroll
    for (int off = 1; off < 64; off <<= 1) s = fmaxf(s, __shfl_xor(s, off));
    qp[group * 64 + m] = MINV * (expf(dd - diag - s) + 1e-6f);
}

// ---- 2b. phi(k) pass 1: store raw dd + diag, atomic per-(b,h) max ----
__global__ __launch_bounds__(256) void phi_k1_kernel(
    const float* __restrict__ kb, const float* __restrict__ proj,
    float* __restrict__ ddout, float* __restrict__ diagout,
    unsigned* __restrict__ kmaxkey)
{
    __shared__ float ps[64 * 33];
    const int t = threadIdx.x;
    for (int j = t; j < 2048; j += 256) ps[(j >> 5) * 33 + (j & 31)] = proj[j];
    __syncthreads();
    const int group = blockIdx.x * 4 + (t >> 6);
    const int m = t & 63;
    const int row = group >> 3;
    const int h = group & 7;
    const float* kptr = kb + row * 256 + h * 32;
    float dd = 0.f, diag = 0.f;
    #pragma unroll
    for (int d = 0; d < 32; ++d) {
        float kv = kptr[d] * PHI_SCALE;
        dd += kv * ps[m * 33 + d];
        diag += kv * kv;
    }
    diag *= 0.5f;
    ddout[group * 64 + m] = dd;
    float s = dd;
    #pragma unroll
    for (int off = 1; off < 64; off <<= 1) s = fmaxf(s, __shfl_xor(s, off));
    if (m == 0) {
        diagout[group] = diag;
        int b = row / L;
        atomicMax(&kmaxkey[b * 8 + h], fkey(s));
    }
}

// ---- 2c. phi(k) pass 2: elementwise finish ----
__global__ __launch_bounds__(256) void phi_k2_kernel(
    float* __restrict__ ddkp, const float* __restrict__ diagk,
    const unsigned* __restrict__ kmaxkey)
{
    const int idx = blockIdx.x * 256 + threadIdx.x;
    if (idx >= B * L * H * M) return;
    const int group = idx >> 6;
    const int h = group & 7;
    const int b = group / (L * H);
    float stab = fkey_inv(kmaxkey[b * 8 + h]);
    float dd = ddkp[idx];
    ddkp[idx] = MINV * (expf(dd - diagk[group] - stab) + 1e-6f);
}

// ---- 3. kvs[b,h,k,m,d] = sum_l kp*eg*v ; ksum = sum_l kp*eg ----
__global__ __launch_bounds__(256) void kvs_kernel(
    const float* __restrict__ kp, const float* __restrict__ vb,
    const float* __restrict__ gum, float* __restrict__ kvs,
    float* __restrict__ ksum)
{
    constexpr int TL = 16;
    __shared__ float kps[TL][64];
    __shared__ float vs[TL][32];
    __shared__ float egs[TL];
    const int bi = blockIdx.x;
    const int b = bi >> 7;            // /(H*KG)
    const int h = (bi >> 4) & 7;
    const int kk = bi & 15;
    const int t = threadIdx.x;
    const int d = t & 31;
    const int mb = (t >> 5) * 8;
    float acc[8] = {0, 0, 0, 0, 0, 0, 0, 0};
    float sacc[8] = {0, 0, 0, 0, 0, 0, 0, 0};
    for (int l0 = 0; l0 < L; l0 += TL) {
        for (int j = t; j < TL * 64; j += 256) {
            int ll = j >> 6, m = j & 63;
            kps[ll][m] = kp[((b * L + l0 + ll) * H + h) * 64 + m];
        }
        for (int j = t; j < TL * 32; j += 256) {
            int ll = j >> 5, d2 = j & 31;
            vs[ll][d2] = vb[(b * L + l0 + ll) * 256 + h * 32 + d2];
        }
        if (t < TL) egs[t] = expf(gum[((b * L + l0 + t) * H + h) * 16 + kk]);
        __syncthreads();
        for (int ll = 0; ll < TL; ++ll) {
            float ev = egs[ll];
            float tmp = ev * vs[ll][d];
            #pragma unroll
            for (int mi = 0; mi < 8; ++mi)
                acc[mi] += kps[ll][mb + mi] * tmp;
            if (d == 0) {
                #pragma unroll
                for (int mi = 0; mi < 8; ++mi)
                    sacc[mi] += kps[ll][mb + mi] * ev;
            }
        }
        __syncthreads();
    }
    const long base = ((long)(b * 8 + h) * 16 + kk) * 2048;
    for (int mi = 0; mi < 8; ++mi)
        kvs[base + (mb + mi) * 32 + d] = acc[mi];
    if (d == 0) {
        const long sb = ((long)(b * 8 + h) * 16 + kk) * 64;
        for (int mi = 0; mi < 8; ++mi) ksum[sb + mb + mi] = sacc[mi];
    }
}

// ---- 4. den[b,l,h,k] = qp . ksum + 1e-8 ----
__global__ __launch_bounds__(128) void den_kernel(
    const float* __restrict__ qp, const float* __restrict__ ksum,
    float* __restrict__ den)
{
    const int row = blockIdx.x;       // b*L + l
    const int t = threadIdx.x;        // 128
    const int h = t >> 4, kk = t & 15;
    const int b = row / L;
    const float* qpr = qp + (row * 8 + h) * 64;
    const float* ksr = ksum + ((b * 8 + h) * 16 + kk) * 64;
    float s = 0.f;
    #pragma unroll 8
    for (int m = 0; m < 64; ++m) s += qpr[m] * ksr[m];
    den[(row * 8 + h) * 16 + kk] = s + 1e-8f;
}

// ---- 5. z = LN(mean_k (qp.kvs)/den) ----
__global__ __launch_bounds__(256) void z_kernel(
    const float* __restrict__ qp, const float* __restrict__ kvs,
    const float* __restrict__ den, const float* __restrict__ ln_g,
    const float* __restrict__ ln_b, float* __restrict__ z)
{
    __shared__ float qps[80 * 64];
    __shared__ float kvss[2048];
    __shared__ float dens[80 * 16];
    const int bi = blockIdx.x;        // B*H*10
    const int b = bi / 80;
    const int h = (bi / 10) & 7;
    const int l0 = (bi % 10) * 80;
    const int t = threadIdx.x;
    const int d = t & 31, lr = t >> 5;
    for (int j = t; j < 80 * 64; j += 256) {
        int ll = j >> 6, m = j & 63;
        qps[j] = qp[((b * L + l0 + ll) * 8 + h) * 64 + m];
    }
    for (int j = t; j < 80 * 16; j += 256) {
        int ll = j >> 4, kk2 = j & 15;
        dens[j] = den[((b * L + l0 + ll) * 8 + h) * 16 + kk2];
    }
    float acc[10];
    #pragma unroll
    for (int i = 0; i < 10; ++i) acc[i] = 0.f;
    for (int kk = 0; kk < 16; ++kk) {
        __syncthreads();
        const float* kbase = kvs + ((long)(b * 8 + h) * 16 + kk) * 2048;
        for (int j = t; j < 2048; j += 256) kvss[j] = kbase[j];
        __syncthreads();
        #pragma unroll
        for (int li = 0; li < 10; ++li) {
            int ll = li * 8 + lr;
            float num = 0.f;
            #pragma unroll
            for (int m = 0; m < 64; ++m)
                num += qps[ll * 64 + m] * kvss[m * 32 + d];
            acc[li] += num / dens[ll * 16 + kk];
        }
    }
    float gg = ln_g[d], bb = ln_b[d];
    for (int li = 0; li < 10; ++li) {
        float zv = acc[li] * (1.0f / 16.0f);
        float s1 = zv, s2 = zv * zv;
        #pragma unroll
        for (int off = 1; off < 32; off <<= 1) {
            s1 += __shfl_xor(s1, off);
            s2 += __shfl_xor(s2, off);
        }
        float mu = s1 * (1.0f / 32.0f);
        float var = s2 * (1.0f / 32.0f) - mu * mu;
        float zn = (zv - mu) * rsqrtf(var + 1e-5f) * gg + bb;
        z[(b * L + l0 + li * 8 + lr) * 256 + h * 32 + d] = zn;
    }
}

// ---- 6. h1 partials: split-K GEMM [512 x 10000] @ [10000 x 128] ----
__global__ __launch_bounds__(256) void adjfc_kernel(
    const float* __restrict__ adj, const float* __restrict__ fcw,
    float* __restrict__ h1part)
{
    __shared__ float fs[128 * 65];    // padded stride 65 -> no bank conflict
    __shared__ float as[8][64];
    const int bi = blockIdx.x;        // 64 * ADJ_SPLIT
    const int bp = bi / ADJ_SPLIT;
    const int sp = bi % ADJ_SPLIT;
    const int b = bp >> 3, p = bp & 7;
    const int k0 = sp * ADJ_KC;
    const int kend = min(k0 + ADJ_KC, NN);
    const int t = threadIdx.x;
    const int c = t & 127, ph = t >> 7;
    float acc[4] = {0.f, 0.f, 0.f, 0.f};
    for (int j0 = k0; j0 < kend; j0 += 64) {
        const int len = min(64, kend - j0);
        for (int j = t; j < 128 * 64; j += 256) {
            int c2 = j >> 6, jj = j & 63;
            fs[c2 * 65 + jj] = (jj < len) ? fcw[(long)c2 * NN + j0 + jj] : 0.f;
        }
        for (int j = t; j < 8 * 64; j += 256) {
            int rr = j >> 6, jj = j & 63;
            as[rr][jj] = (jj < len) ? adj[((long)(b * 64 + p * 8 + rr)) * NN + j0 + jj] : 0.f;
        }
        __syncthreads();
        #pragma unroll 8
        for (int jj = 0; jj < 64; ++jj) {
            float wv = fs[c * 65 + jj];
            #pragma unroll
            for (int r4 = 0; r4 < 4; ++r4)
                acc[r4] += as[ph + r4 * 2][jj] * wv;
        }
        __syncthreads();
    }
    for (int r4 = 0; r4 < 4; ++r4) {
        int pl = ph + r4 * 2;
        h1part[((sp * 64 + bp) * 8 + pl) * 128 + c] = acc[r4];
    }
}

// ---- 7. w = softmax over patch_len; absorbs split-reduce + bias + relu ----
__global__ __launch_bounds__(128) void wsm_kernel(
    const float* __restrict__ h1part, const float* __restrict__ fcb,
    const float* __restrict__ ow, const float* __restrict__ ob,
    float* __restrict__ wsm)
{
    __shared__ float part[8][2];
    const int bp = blockIdx.x;
    const int t = threadIdx.x;   // 128
    float owv = ow[t], bb = fcb[t];
    for (int pl = 0; pl < 8; ++pl) {
        float h = 0.f;
        for (int s = 0; s < ADJ_SPLIT; ++s)
            h += h1part[((s * 64 + bp) * 8 + pl) * 128 + t];
        float v = fmaxf(h + bb, 0.f) * owv;
        #pragma unroll
        for (int off = 1; off < 64; off <<= 1) v += __shfl_xor(v, off);
        if ((t & 63) == 0) part[pl][t >> 6] = v;
    }
    __syncthreads();
    if (t == 0) {
        float lg[8], mx = -1e30f;
        for (int pl = 0; pl < 8; ++pl) {
            lg[pl] = part[pl][0] + part[pl][1] + ob[0];
            mx = fmaxf(mx, lg[pl]);
        }
        float s = 0.f;
        for (int pl = 0; pl < 8; ++pl) { lg[pl] = expf(lg[pl] - mx); s += lg[pl]; }
        for (int pl = 0; pl < 8; ++pl) wsm[bp * 8 + pl] = lg[pl] / s;
    }
}

// ---- 8. fused + row L1-normalize ----
__global__ __launch_bounds__(128) void fused_kernel(
    const float* __restrict__ adj, const float* __restrict__ wsm,
    float* __restrict__ fusedn)
{
    __shared__ float part[2];
    const int bi = blockIdx.x;        // (b*8+p)*100 + i
    const int b = bi / 800;
    const int p = (bi / 100) & 7;
    const int i = bi % 100;
    const int t = threadIdx.x;        // 128
    float f = 0.f;
    if (t < 100) {
        #pragma unroll
        for (int pl = 0; pl < 8; ++pl)
            f += adj[((long)(b * 64 + p * 8 + pl)) * NN + i * 100 + t] * wsm[(b * 8 + p) * 8 + pl];
    }
    float a = fabsf(f);
    #pragma unroll
    for (int off = 1; off < 64; off <<= 1) a += __shfl_xor(a, off);
    if ((t & 63) == 0) part[t >> 6] = a;
    __syncthreads();
    float denom = fmaxf(part[0] + part[1], 1e-12f);
    if (t < 100) fusedn[(long)bi * 100 + t] = f / denom;
}

// ---- 9. z += block-diag(fusedn) @ v  (10 rows per block) ----
__global__ __launch_bounds__(256) void bias_kernel(
    const float* __restrict__ fusedn, const float* __restrict__ vb,
    float* __restrict__ z)
{
    __shared__ float fs[10 * 100];
    const int bi = blockIdx.x;        // 64*10
    const int bp = bi / 10;
    const int b = bp >> 3, p = bp & 7;
    const int i0 = (bi % 10) * 10;
    const int t = threadIdx.x;
    for (int j = t; j < 1000; j += 256)
        fs[j] = fusedn[(long)bp * 10000 + i0 * 100 + j];
    __syncthreads();
    float acc[10];
    #pragma unroll
    for (int r = 0; r < 10; ++r) acc[r] = 0.f;
    for (int j = 0; j < 100; ++j) {
        float vj = vb[(b * 800 + p * 100 + j) * 256 + t];
        #pragma unroll
        for (int r = 0; r < 10; ++r)
            acc[r] += fs[r * 100 + j] * vj;
    }
    for (int r = 0; r < 10; ++r)
        z[(b * 800 + p * 100 + i0 + r) * 256 + t] += acc[r];
}

// ---- 10. out = zb @ Wo^T + bo (float4 weight loads) ----
__global__ __launch_bounds__(256) void out_kernel(
    const float* __restrict__ z, const float* __restrict__ Wo,
    const float* __restrict__ bo, float* __restrict__ out)
{
    __shared__ float zs[8][256];
    const int row0 = blockIdx.x * 8;
    const int t = threadIdx.x;
    for (int r = 0; r < 8; ++r) zs[r][t] = z[(row0 + r) * 256 + t];
    __syncthreads();
    float acc[8];
    #pragma unroll
    for (int r = 0; r < 8; ++r) acc[r] = 0.f;
    const float4* w4 = reinterpret_cast<const float4*>(Wo) + t * 64;
    for (int kk = 0; kk < 64; ++kk) {
        float4 wv = w4[kk];
        #pragma unroll
        for (int r = 0; r < 8; ++r) {
            const float* zr = &zs[r][kk * 4];
            acc[r] += zr[0] * wv.x + zr[1] * wv.y + zr[2] * wv.z + zr[3] * wv.w;
        }
    }
    float bb = bo[t];
    for (int r = 0; r < 8; ++r) out[(row0 + r) * 256 + t] = acc[r] + bb;
}

extern "C" void kernel_launch(void* const* d_in, const int* in_sizes, int n_in,
                              void* d_out, int out_size, void* d_ws, size_t ws_size,
                              hipStream_t stream) {
    const float* x     = (const float*)d_in[0];
    const float* adj   = (const float*)d_in[1];
    const float* Wq_w  = (const float*)d_in[2];
    const float* Wq_b  = (const float*)d_in[3];
    const float* Wk_w  = (const float*)d_in[4];
    const float* Wk_b  = (const float*)d_in[5];
    const float* Wv_w  = (const float*)d_in[6];
    const float* Wv_b  = (const float*)d_in[7];
    const float* Wo_w  = (const float*)d_in[8];
    const float* Wo_b  = (const float*)d_in[9];
    const float* ln_g  = (const float*)d_in[10];
    const float* ln_b  = (const float*)d_in[11];
    const float* fc_w  = (const float*)d_in[12];
    const float* fc_b  = (const float*)d_in[13];
    const float* out_w = (const float*)d_in[14];
    const float* out_b = (const float*)d_in[15];
    const float* proj  = (const float*)d_in[16];
    const float* gum   = (const float*)d_in[17];
    float* out = (float*)d_out;

    // workspace layout (floats)
    float* ws = (float*)d_ws;
    size_t off = 0;
    float* qbuf   = ws + off; off += (size_t)B * L * 256;      // 1,638,400
    float* kbuf   = ws + off; off += (size_t)B * L * 256;
    float* vbuf   = ws + off; off += (size_t)B * L * 256;
    float* qp     = ws + off; off += (size_t)B * L * H * M;    // 3,276,800
    float* kp     = ws + off; off += (size_t)B * L * H * M;
    float* diagk  = ws + off; off += (size_t)B * L * H;        // 51,200
    float* kvs    = ws + off; off += (size_t)B * H * KG * M * DK; // 2,097,152
    float* ksum   = ws + off; off += (size_t)B * H * KG * M;   // 65,536
    float* den    = ws + off; off += (size_t)B * L * H * KG;   // 819,200
    float* zbuf   = ws + off; off += (size_t)B * L * 256;      // 1,638,400
    float* h1part = ws + off; off += (size_t)ADJ_SPLIT * 64 * 8 * 128; // 1,310,720
    float* wsm    = ws + off; off += 512;
    float* fusedn = ws + off; off += (size_t)64 * NN;          // 640,000
    unsigned* kmaxkey = (unsigned*)(ws + off); off += 64;

    hipMemsetAsync(kmaxkey, 0, 64 * sizeof(unsigned), stream);

    qkv_kernel<<<800, 256, 0, stream>>>(x, Wq_w, Wq_b, Wk_w, Wk_b, Wv_w, Wv_b,
                                        qbuf, kbuf, vbuf);
    phi_q_kernel<<<12800, 256, 0, stream>>>(qbuf, proj, qp);
    phi_k1_kernel<<<12800, 256, 0, stream>>>(kbuf, proj, kp, diagk, kmaxkey);
    phi_k2_kernel<<<12800, 256, 0, stream>>>(kp, diagk, kmaxkey);
    kvs_kernel<<<1024, 256, 0, stream>>>(kp, vbuf, gum, kvs, ksum);
    den_kernel<<<6400, 128, 0, stream>>>(qp, ksum, den);
    z_kernel<<<640, 256, 0, stream>>>(qp, kvs, den, ln_g, ln_b, zbuf);
    adjfc_kernel<<<64 * ADJ_SPLIT, 256, 0, stream>>>(adj, fc_w, h1part);
    wsm_kernel<<<64, 128, 0, stream>>>(h1part, fc_b, out_w, out_b, wsm);
    fused_kernel<<<6400, 128, 0, stream>>>(adj, wsm, fusedn);
    bias_kernel<<<640, 256, 0, stream>>>(fusedn, vbuf, zbuf);
    out_kernel<<<800, 256, 0, stream>>>(zbuf, Wo_w, Wo_b, out);
}

// Round 3
// 1082.175 us; speedup vs baseline: 1.5839x; 1.3249x over previous
//
#include <hip/hip_runtime.h>
#include <cstdint>

// ---- static config ----
constexpr int B = 8, P = 8, N = 100, D = 256, H = 8, DK = 32, M = 64, KG = 16;
constexpr int L = P * N;      // 800
constexpr int PATCH = 8;
constexpr int NN = N * N;     // 10000
constexpr float PHI_SCALE = 0.8408964152537145f;  // (1/sqrt(0.25)) * 32^-0.25
constexpr float MINV = 0.125f;                    // 64^-0.5
constexpr int ADJ_SPLIT = 20;                     // split-K for adjfc GEMM
constexpr int ADJ_KC = 512;                       // K-chunk (last = 272)

// ---- 1. q,k,v = xt @ W^T + b (three at once, float4 weight loads) ----
__global__ __launch_bounds__(256) void qkv_kernel(
    const float* __restrict__ x,
    const float* __restrict__ Wq, const float* __restrict__ bq,
    const float* __restrict__ Wk, const float* __restrict__ bk,
    const float* __restrict__ Wv, const float* __restrict__ bv,
    float* __restrict__ q, float* __restrict__ k, float* __restrict__ v)
{
    __shared__ float xs[8][256];
    const int row0 = blockIdx.x * 8;
    const int t = threadIdx.x;
    for (int r = 0; r < 8; ++r) xs[r][t] = x[(row0 + r) * 256 + t];
    __syncthreads();
    float aq[8], ak[8], av[8];
    #pragma unroll
    for (int r = 0; r < 8; ++r) { aq[r] = 0.f; ak[r] = 0.f; av[r] = 0.f; }
    const float4* wq4 = reinterpret_cast<const float4*>(Wq) + t * 64;
    const float4* wk4 = reinterpret_cast<const float4*>(Wk) + t * 64;
    const float4* wv4 = reinterpret_cast<const float4*>(Wv) + t * 64;
    for (int kk = 0; kk < 64; ++kk) {
        float4 wqv = wq4[kk], wkv = wk4[kk], wvv = wv4[kk];
        #pragma unroll
        for (int r = 0; r < 8; ++r) {
            const float* xr = &xs[r][kk * 4];
            aq[r] += xr[0] * wqv.x + xr[1] * wqv.y + xr[2] * wqv.z + xr[3] * wqv.w;
            ak[r] += xr[0] * wkv.x + xr[1] * wkv.y + xr[2] * wkv.z + xr[3] * wkv.w;
            av[r] += xr[0] * wvv.x + xr[1] * wvv.y + xr[2] * wvv.z + xr[3] * wvv.w;
        }
    }
    float bqv = bq[t], bkv = bk[t], bvv = bv[t];
    for (int r = 0; r < 8; ++r) {
        q[(row0 + r) * 256 + t] = aq[r] + bqv;
        k[(row0 + r) * 256 + t] = ak[r] + bkv;
        v[(row0 + r) * 256 + t] = av[r] + bvv;
    }
}

// ---- 2a. phi(q): one 64-lane group per (b,l,h), lane = m ----
__global__ __launch_bounds__(256) void phi_q_kernel(
    const float* __restrict__ qb, const float* __restrict__ proj,
    float* __restrict__ qp)
{
    __shared__ float ps[64 * 33];
    const int t = threadIdx.x;
    for (int j = t; j < 2048; j += 256) ps[(j >> 5) * 33 + (j & 31)] = proj[j];
    __syncthreads();
    const int group = blockIdx.x * 4 + (t >> 6);
    const int m = t & 63;
    const int row = group >> 3;
    const int h = group & 7;
    const float* qptr = qb + row * 256 + h * 32;
    float dd = 0.f, diag = 0.f;
    #pragma unroll
    for (int d = 0; d < 32; ++d) {
        float qv = qptr[d] * PHI_SCALE;
        dd += qv * ps[m * 33 + d];
        diag += qv * qv;
    }
    diag *= 0.5f;
    float s = dd;
    #pragma unroll
    for (int off = 1; off < 64; off <<= 1) s = fmaxf(s, __shfl_xor(s, off));
    qp[group * 64 + m] = MINV * (expf(dd - diag - s) + 1e-6f);
}

// ---- 2b. phi(k) pass 1: blocks grouped by (b,h); block-max -> partial, NO atomics ----
__global__ __launch_bounds__(256) void phi_k1_kernel(
    const float* __restrict__ kb, const float* __restrict__ proj,
    float* __restrict__ ddout, float* __restrict__ diagout,
    float* __restrict__ partmax)
{
    __shared__ float ps[64 * 33];
    __shared__ float wmax[4];
    const int t = threadIdx.x;
    for (int j = t; j < 2048; j += 256) ps[(j >> 5) * 33 + (j & 31)] = proj[j];
    __syncthreads();
    const int bi = blockIdx.x;        // 64 * 200
    const int bh = bi / 200;
    const int l = (bi % 200) * 4 + (t >> 6);
    const int m = t & 63;
    const int b = bh >> 3, h = bh & 7;
    const float* kptr = kb + (b * L + l) * 256 + h * 32;
    float dd = 0.f, diag = 0.f;
    #pragma unroll
    for (int d = 0; d < 32; ++d) {
        float kv = kptr[d] * PHI_SCALE;
        dd += kv * ps[m * 33 + d];
        diag += kv * kv;
    }
    diag *= 0.5f;
    const int group = (b * L + l) * H + h;
    ddout[group * 64 + m] = dd;
    float s = dd;
    #pragma unroll
    for (int off = 1; off < 64; off <<= 1) s = fmaxf(s, __shfl_xor(s, off));
    if (m == 0) {
        diagout[group] = diag;
        wmax[t >> 6] = s;
    }
    __syncthreads();
    if (t == 0)
        partmax[bi] = fmaxf(fmaxf(wmax[0], wmax[1]), fmaxf(wmax[2], wmax[3]));
}

// ---- 2b'. reduce 200 partials -> kmax[bh] ----
__global__ __launch_bounds__(64) void kmax_kernel(
    const float* __restrict__ partmax, float* __restrict__ kmax)
{
    const int bh = blockIdx.x;
    const int t = threadIdx.x;
    float s = -1e30f;
    for (int i = t; i < 200; i += 64) s = fmaxf(s, partmax[bh * 200 + i]);
    #pragma unroll
    for (int off = 1; off < 64; off <<= 1) s = fmaxf(s, __shfl_xor(s, off));
    if (t == 0) kmax[bh] = s;
}

// ---- 2c. phi(k) pass 2: elementwise finish ----
__global__ __launch_bounds__(256) void phi_k2_kernel(
    float* __restrict__ ddkp, const float* __restrict__ diagk,
    const float* __restrict__ kmax)
{
    const int idx = blockIdx.x * 256 + threadIdx.x;
    if (idx >= B * L * H * M) return;
    const int group = idx >> 6;
    const int h = group & 7;
    const int b = group / (L * H);
    float stab = kmax[b * 8 + h];
    float dd = ddkp[idx];
    ddkp[idx] = MINV * (expf(dd - diagk[group] - stab) + 1e-6f);
}

// ---- 3. kvs[b,h,k,m,d] = sum_l kp*eg*v ; ksum = sum_l kp*eg ----
__global__ __launch_bounds__(256) void kvs_kernel(
    const float* __restrict__ kp, const float* __restrict__ vb,
    const float* __restrict__ gum, float* __restrict__ kvs,
    float* __restrict__ ksum)
{
    constexpr int TL = 16;
    __shared__ float kps[TL][64];
    __shared__ float vs[TL][32];
    __shared__ float egs[TL];
    const int bi = blockIdx.x;
    const int b = bi >> 7;            // /(H*KG)
    const int h = (bi >> 4) & 7;
    const int kk = bi & 15;
    const int t = threadIdx.x;
    const int d = t & 31;
    const int mb = (t >> 5) * 8;
    float acc[8] = {0, 0, 0, 0, 0, 0, 0, 0};
    float sacc[8] = {0, 0, 0, 0, 0, 0, 0, 0};
    for (int l0 = 0; l0 < L; l0 += TL) {
        for (int j = t; j < TL * 64; j += 256) {
            int ll = j >> 6, m = j & 63;
            kps[ll][m] = kp[((b * L + l0 + ll) * H + h) * 64 + m];
        }
        for (int j = t; j < TL * 32; j += 256) {
            int ll = j >> 5, d2 = j & 31;
            vs[ll][d2] = vb[(b * L + l0 + ll) * 256 + h * 32 + d2];
        }
        if (t < TL) egs[t] = expf(gum[((b * L + l0 + t) * H + h) * 16 + kk]);
        __syncthreads();
        for (int ll = 0; ll < TL; ++ll) {
            float ev = egs[ll];
            float tmp = ev * vs[ll][d];
            #pragma unroll
            for (int mi = 0; mi < 8; ++mi)
                acc[mi] += kps[ll][mb + mi] * tmp;
            if (d == 0) {
                #pragma unroll
                for (int mi = 0; mi < 8; ++mi)
                    sacc[mi] += kps[ll][mb + mi] * ev;
            }
        }
        __syncthreads();
    }
    const long base = ((long)(b * 8 + h) * 16 + kk) * 2048;
    for (int mi = 0; mi < 8; ++mi)
        kvs[base + (mb + mi) * 32 + d] = acc[mi];
    if (d == 0) {
        const long sb = ((long)(b * 8 + h) * 16 + kk) * 64;
        for (int mi = 0; mi < 8; ++mi) ksum[sb + mb + mi] = sacc[mi];
    }
}

// ---- 4. den[b,l,h,k] = qp . ksum + 1e-8 ----
__global__ __launch_bounds__(128) void den_kernel(
    const float* __restrict__ qp, const float* __restrict__ ksum,
    float* __restrict__ den)
{
    const int row = blockIdx.x;       // b*L + l
    const int t = threadIdx.x;        // 128
    const int h = t >> 4, kk = t & 15;
    const int b = row / L;
    const float* qpr = qp + (row * 8 + h) * 64;
    const float* ksr = ksum + ((b * 8 + h) * 16 + kk) * 64;
    float s = 0.f;
    #pragma unroll 8
    for (int m = 0; m < 64; ++m) s += qpr[m] * ksr[m];
    den[(row * 8 + h) * 16 + kk] = s + 1e-8f;
}

// ---- 5. z = LN(mean_k (qp.kvs)/den) ----
__global__ __launch_bounds__(256) void z_kernel(
    const float* __restrict__ qp, const float* __restrict__ kvs,
    const float* __restrict__ den, const float* __restrict__ ln_g,
    const float* __restrict__ ln_b, float* __restrict__ z)
{
    __shared__ float qps[80 * 64];
    __shared__ float kvss[2048];
    __shared__ float dens[80 * 16];
    const int bi = blockIdx.x;        // B*H*10
    const int b = bi / 80;
    const int h = (bi / 10) & 7;
    const int l0 = (bi % 10) * 80;
    const int t = threadIdx.x;
    const int d = t & 31, lr = t >> 5;
    for (int j = t; j < 80 * 64; j += 256) {
        int ll = j >> 6, m = j & 63;
        qps[j] = qp[((b * L + l0 + ll) * 8 + h) * 64 + m];
    }
    for (int j = t; j < 80 * 16; j += 256) {
        int ll = j >> 4, kk2 = j & 15;
        dens[j] = 1.0f / den[((b * L + l0 + ll) * 8 + h) * 16 + kk2];
    }
    float acc[10];
    #pragma unroll
    for (int i = 0; i < 10; ++i) acc[i] = 0.f;
    for (int kk = 0; kk < 16; ++kk) {
        __syncthreads();
        const float* kbase = kvs + ((long)(b * 8 + h) * 16 + kk) * 2048;
        for (int j = t; j < 2048; j += 256) kvss[j] = kbase[j];
        __syncthreads();
        #pragma unroll
        for (int li = 0; li < 10; ++li) {
            int ll = li * 8 + lr;
            float num = 0.f;
            #pragma unroll
            for (int m = 0; m < 64; ++m)
                num += qps[ll * 64 + m] * kvss[m * 32 + d];
            acc[li] += num * dens[ll * 16 + kk];
        }
    }
    float gg = ln_g[d], bb = ln_b[d];
    for (int li = 0; li < 10; ++li) {
        float zv = acc[li] * (1.0f / 16.0f);
        float s1 = zv, s2 = zv * zv;
        #pragma unroll
        for (int off = 1; off < 32; off <<= 1) {
            s1 += __shfl_xor(s1, off);
            s2 += __shfl_xor(s2, off);
        }
        float mu = s1 * (1.0f / 32.0f);
        float var = s2 * (1.0f / 32.0f) - mu * mu;
        float zn = (zv - mu) * rsqrtf(var + 1e-5f) * gg + bb;
        z[(b * L + l0 + li * 8 + lr) * 256 + h * 32 + d] = zn;
    }
}

// ---- 6. h1 partials: split-K GEMM [512 x 10000] @ [10000 x 128] ----
__global__ __launch_bounds__(256) void adjfc_kernel(
    const float* __restrict__ adj, const float* __restrict__ fcw,
    float* __restrict__ h1part)
{
    __shared__ float fs[128 * 65];    // padded stride 65 -> no bank conflict
    __shared__ float as[8][64];
    const int bi = blockIdx.x;        // 64 * ADJ_SPLIT
    const int bp = bi / ADJ_SPLIT;
    const int sp = bi % ADJ_SPLIT;
    const int b = bp >> 3, p = bp & 7;
    const int k0 = sp * ADJ_KC;
    const int kend = min(k0 + ADJ_KC, NN);
    const int t = threadIdx.x;
    const int c = t & 127, ph = t >> 7;
    float acc[4] = {0.f, 0.f, 0.f, 0.f};
    for (int j0 = k0; j0 < kend; j0 += 64) {
        const int len = min(64, kend - j0);
        for (int j = t; j < 128 * 64; j += 256) {
            int c2 = j >> 6, jj = j & 63;
            fs[c2 * 65 + jj] = (jj < len) ? fcw[(long)c2 * NN + j0 + jj] : 0.f;
        }
        for (int j = t; j < 8 * 64; j += 256) {
            int rr = j >> 6, jj = j & 63;
            as[rr][jj] = (jj < len) ? adj[((long)(b * 64 + p * 8 + rr)) * NN + j0 + jj] : 0.f;
        }
        __syncthreads();
        #pragma unroll 8
        for (int jj = 0; jj < 64; ++jj) {
            float wv = fs[c * 65 + jj];
            #pragma unroll
            for (int r4 = 0; r4 < 4; ++r4)
                acc[r4] += as[ph + r4 * 2][jj] * wv;
        }
        __syncthreads();
    }
    for (int r4 = 0; r4 < 4; ++r4) {
        int pl = ph + r4 * 2;
        h1part[((sp * 64 + bp) * 8 + pl) * 128 + c] = acc[r4];
    }
}

// ---- 7. w = softmax over patch_len; absorbs split-reduce + bias + relu ----
__global__ __launch_bounds__(128) void wsm_kernel(
    const float* __restrict__ h1part, const float* __restrict__ fcb,
    const float* __restrict__ ow, const float* __restrict__ ob,
    float* __restrict__ wsm)
{
    __shared__ float part[8][2];
    const int bp = blockIdx.x;
    const int t = threadIdx.x;   // 128
    float owv = ow[t], bb = fcb[t];
    for (int pl = 0; pl < 8; ++pl) {
        float h = 0.f;
        for (int s = 0; s < ADJ_SPLIT; ++s)
            h += h1part[((s * 64 + bp) * 8 + pl) * 128 + t];
        float v = fmaxf(h + bb, 0.f) * owv;
        #pragma unroll
        for (int off = 1; off < 64; off <<= 1) v += __shfl_xor(v, off);
        if ((t & 63) == 0) part[pl][t >> 6] = v;
    }
    __syncthreads();
    if (t == 0) {
        float lg[8], mx = -1e30f;
        for (int pl = 0; pl < 8; ++pl) {
            lg[pl] = part[pl][0] + part[pl][1] + ob[0];
            mx = fmaxf(mx, lg[pl]);
        }
        float s = 0.f;
        for (int pl = 0; pl < 8; ++pl) { lg[pl] = expf(lg[pl] - mx); s += lg[pl]; }
        for (int pl = 0; pl < 8; ++pl) wsm[bp * 8 + pl] = lg[pl] / s;
    }
}

// ---- 8. fused + row L1-normalize ----
__global__ __launch_bounds__(128) void fused_kernel(
    const float* __restrict__ adj, const float* __restrict__ wsm,
    float* __restrict__ fusedn)
{
    __shared__ float part[2];
    const int bi = blockIdx.x;        // (b*8+p)*100 + i
    const int b = bi / 800;
    const int p = (bi / 100) & 7;
    const int i = bi % 100;
    const int t = threadIdx.x;        // 128
    float f = 0.f;
    if (t < 100) {
        #pragma unroll
        for (int pl = 0; pl < 8; ++pl)
            f += adj[((long)(b * 64 + p * 8 + pl)) * NN + i * 100 + t] * wsm[(b * 8 + p) * 8 + pl];
    }
    float a = fabsf(f);
    #pragma unroll
    for (int off = 1; off < 64; off <<= 1) a += __shfl_xor(a, off);
    if ((t & 63) == 0) part[t >> 6] = a;
    __syncthreads();
    float denom = fmaxf(part[0] + part[1], 1e-12f);
    if (t < 100) fusedn[(long)bi * 100 + t] = f / denom;
}

// ---- 9. z += block-diag(fusedn) @ v  (10 rows per block) ----
__global__ __launch_bounds__(256) void bias_kernel(
    const float* __restrict__ fusedn, const float* __restrict__ vb,
    float* __restrict__ z)
{
    __shared__ float fs[10 * 100];
    const int bi = blockIdx.x;        // 64*10
    const int bp = bi / 10;
    const int b = bp >> 3, p = bp & 7;
    const int i0 = (bi % 10) * 10;
    const int t = threadIdx.x;
    for (int j = t; j < 1000; j += 256)
        fs[j] = fusedn[(long)bp * 10000 + i0 * 100 + j];
    __syncthreads();
    float acc[10];
    #pragma unroll
    for (int r = 0; r < 10; ++r) acc[r] = 0.f;
    for (int j = 0; j < 100; ++j) {
        float vj = vb[(b * 800 + p * 100 + j) * 256 + t];
        #pragma unroll
        for (int r = 0; r < 10; ++r)
            acc[r] += fs[r * 100 + j] * vj;
    }
    for (int r = 0; r < 10; ++r)
        z[(b * 800 + p * 100 + i0 + r) * 256 + t] += acc[r];
}

// ---- 10. out = zb @ Wo^T + bo (float4 weight loads) ----
__global__ __launch_bounds__(256) void out_kernel(
    const float* __restrict__ z, const float* __restrict__ Wo,
    const float* __restrict__ bo, float* __restrict__ out)
{
    __shared__ float zs[8][256];
    const int row0 = blockIdx.x * 8;
    const int t = threadIdx.x;
    for (int r = 0; r < 8; ++r) zs[r][t] = z[(row0 + r) * 256 + t];
    __syncthreads();
    float acc[8];
    #pragma unroll
    for (int r = 0; r < 8; ++r) acc[r] = 0.f;
    const float4* w4 = reinterpret_cast<const float4*>(Wo) + t * 64;
    for (int kk = 0; kk < 64; ++kk) {
        float4 wv = w4[kk];
        #pragma unroll
        for (int r = 0; r < 8; ++r) {
            const float* zr = &zs[r][kk * 4];
            acc[r] += zr[0] * wv.x + zr[1] * wv.y + zr[2] * wv.z + zr[3] * wv.w;
        }
    }
    float bb = bo[t];
    for (int r = 0; r < 8; ++r) out[(row0 + r) * 256 + t] = acc[r] + bb;
}

extern "C" void kernel_launch(void* const* d_in, const int* in_sizes, int n_in,
                              void* d_out, int out_size, void* d_ws, size_t ws_size,
                              hipStream_t stream) {
    const float* x     = (const float*)d_in[0];
    const float* adj   = (const float*)d_in[1];
    const float* Wq_w  = (const float*)d_in[2];
    const float* Wq_b  = (const float*)d_in[3];
    const float* Wk_w  = (const float*)d_in[4];
    const float* Wk_b  = (const float*)d_in[5];
    const float* Wv_w  = (const float*)d_in[6];
    const float* Wv_b  = (const float*)d_in[7];
    const float* Wo_w  = (const float*)d_in[8];
    const float* Wo_b  = (const float*)d_in[9];
    const float* ln_g  = (const float*)d_in[10];
    const float* ln_b  = (const float*)d_in[11];
    const float* fc_w  = (const float*)d_in[12];
    const float* fc_b  = (const float*)d_in[13];
    const float* out_w = (const float*)d_in[14];
    const float* out_b = (const float*)d_in[15];
    const float* proj  = (const float*)d_in[16];
    const float* gum   = (const float*)d_in[17];
    float* out = (float*)d_out;

    // workspace layout (floats)
    float* ws = (float*)d_ws;
    size_t off = 0;
    float* qbuf   = ws + off; off += (size_t)B * L * 256;      // 1,638,400
    float* kbuf   = ws + off; off += (size_t)B * L * 256;
    float* vbuf   = ws + off; off += (size_t)B * L * 256;
    float* qp     = ws + off; off += (size_t)B * L * H * M;    // 3,276,800
    float* kp     = ws + off; off += (size_t)B * L * H * M;
    float* diagk  = ws + off; off += (size_t)B * L * H;        // 51,200
    float* kvs    = ws + off; off += (size_t)B * H * KG * M * DK; // 2,097,152
    float* ksum   = ws + off; off += (size_t)B * H * KG * M;   // 65,536
    float* den    = ws + off; off += (size_t)B * L * H * KG;   // 819,200
    float* zbuf   = ws + off; off += (size_t)B * L * 256;      // 1,638,400
    float* h1part = ws + off; off += (size_t)ADJ_SPLIT * 64 * 8 * 128; // 1,310,720
    float* wsm    = ws + off; off += 512;
    float* fusedn = ws + off; off += (size_t)64 * NN;          // 640,000
    float* partmax = ws + off; off += 12800;
    float* kmax    = ws + off; off += 64;

    qkv_kernel<<<800, 256, 0, stream>>>(x, Wq_w, Wq_b, Wk_w, Wk_b, Wv_w, Wv_b,
                                        qbuf, kbuf, vbuf);
    phi_q_kernel<<<12800, 256, 0, stream>>>(qbuf, proj, qp);
    phi_k1_kernel<<<12800, 256, 0, stream>>>(kbuf, proj, kp, diagk, partmax);
    kmax_kernel<<<64, 64, 0, stream>>>(partmax, kmax);
    phi_k2_kernel<<<12800, 256, 0, stream>>>(kp, diagk, kmax);
    kvs_kernel<<<1024, 256, 0, stream>>>(kp, vbuf, gum, kvs, ksum);
    den_kernel<<<6400, 128, 0, stream>>>(qp, ksum, den);
    z_kernel<<<640, 256, 0, stream>>>(qp, kvs, den, ln_g, ln_b, zbuf);
    adjfc_kernel<<<64 * ADJ_SPLIT, 256, 0, stream>>>(adj, fc_w, h1part);
    wsm_kernel<<<64, 128, 0, stream>>>(h1part, fc_b, out_w, out_b, wsm);
    fused_kernel<<<6400, 128, 0, stream>>>(adj, wsm, fusedn);
    bias_kernel<<<640, 256, 0, stream>>>(fusedn, vbuf, zbuf);
    out_kernel<<<800, 256, 0, stream>>>(zbuf, Wo_w, Wo_b, out);
}

// Round 4
// 746.897 us; speedup vs baseline: 2.2949x; 1.4489x over previous
//
#include <hip/hip_runtime.h>
#include <cstdint>

// ---- static config ----
constexpr int B = 8, P = 8, N = 100, D = 256, H = 8, DK = 32, M = 64, KG = 16;
constexpr int L = P * N;      // 800
constexpr int NN = N * N;     // 10000
constexpr float PHI_SCALE = 0.8408964152537145f;  // (1/sqrt(0.25)) * 32^-0.25
constexpr float MINV = 0.125f;                    // 64^-0.5
constexpr int ADJ_SPLIT = 20;                     // split-K for adjfc GEMM
constexpr int ADJ_KC = 512;                       // K-chunk (last = 272)
constexpr int KVS_SPLIT = 3;                      // l-splits for kvs

// ---- 1. q,k,v = xt @ W^T + b (three at once, float4 weight loads) ----
__global__ __launch_bounds__(256) void qkv_kernel(
    const float* __restrict__ x,
    const float* __restrict__ Wq, const float* __restrict__ bq,
    const float* __restrict__ Wk, const float* __restrict__ bk,
    const float* __restrict__ Wv, const float* __restrict__ bv,
    float* __restrict__ q, float* __restrict__ k, float* __restrict__ v)
{
    __shared__ float xs[8][256];
    const int row0 = blockIdx.x * 8;
    const int t = threadIdx.x;
    for (int r = 0; r < 8; ++r) xs[r][t] = x[(row0 + r) * 256 + t];
    __syncthreads();
    float aq[8], ak[8], av[8];
    #pragma unroll
    for (int r = 0; r < 8; ++r) { aq[r] = 0.f; ak[r] = 0.f; av[r] = 0.f; }
    const float4* wq4 = reinterpret_cast<const float4*>(Wq) + t * 64;
    const float4* wk4 = reinterpret_cast<const float4*>(Wk) + t * 64;
    const float4* wv4 = reinterpret_cast<const float4*>(Wv) + t * 64;
    for (int kk = 0; kk < 64; ++kk) {
        float4 wqv = wq4[kk], wkv = wk4[kk], wvv = wv4[kk];
        #pragma unroll
        for (int r = 0; r < 8; ++r) {
            const float* xr = &xs[r][kk * 4];
            aq[r] += xr[0] * wqv.x + xr[1] * wqv.y + xr[2] * wqv.z + xr[3] * wqv.w;
            ak[r] += xr[0] * wkv.x + xr[1] * wkv.y + xr[2] * wkv.z + xr[3] * wkv.w;
            av[r] += xr[0] * wvv.x + xr[1] * wvv.y + xr[2] * wvv.z + xr[3] * wvv.w;
        }
    }
    float bqv = bq[t], bkv = bk[t], bvv = bv[t];
    for (int r = 0; r < 8; ++r) {
        q[(row0 + r) * 256 + t] = aq[r] + bqv;
        k[(row0 + r) * 256 + t] = ak[r] + bkv;
        v[(row0 + r) * 256 + t] = av[r] + bvv;
    }
}

// ---- 2. phi(q) and phi(k) pass1 in one kernel. 32 (b,l,h)-groups per block,
//      proj staged once per block. q: full transform. k: raw dd + diag + block max.
__global__ __launch_bounds__(256) void phiqk_kernel(
    const float* __restrict__ qb, const float* __restrict__ kb,
    const float* __restrict__ proj,
    float* __restrict__ qp, float* __restrict__ ddout,
    float* __restrict__ diagout, float* __restrict__ partmax)
{
    __shared__ float ps[64 * 33];
    __shared__ float wmax[4];
    const int t = threadIdx.x;
    for (int j = t; j < 2048; j += 256) ps[(j >> 5) * 33 + (j & 31)] = proj[j];
    __syncthreads();
    const int bi = blockIdx.x;            // 3200: [0,1600) q, [1600,3200) k
    const bool isq = bi < 1600;
    const int rb = isq ? bi : bi - 1600;
    const int bh = rb / 25;
    const int b = bh >> 3, h = bh & 7;
    const int lbase = (rb % 25) * 32;
    const int wi = t >> 6;                // wave 0..3
    const int m = t & 63;
    const float* src = isq ? qb : kb;
    float rmax = -1e30f;
    for (int si = 0; si < 8; ++si) {
        const int l = lbase + si * 4 + wi;
        const float* ptr = src + (b * L + l) * 256 + h * 32;
        float dd = 0.f, diag = 0.f;
        #pragma unroll
        for (int d2 = 0; d2 < 32; ++d2) {
            float xv = ptr[d2] * PHI_SCALE;
            dd += xv * ps[m * 33 + d2];
            diag += xv * xv;
        }
        diag *= 0.5f;
        float s = dd;
        #pragma unroll
        for (int off = 1; off < 64; off <<= 1) s = fmaxf(s, __shfl_xor(s, off));
        const int group = (b * L + l) * 8 + h;
        if (isq) {
            qp[group * 64 + m] = MINV * (expf(dd - diag - s) + 1e-6f);
        } else {
            ddout[group * 64 + m] = dd;
            if (m == 0) diagout[group] = diag;
            rmax = fmaxf(rmax, s);
        }
    }
    if (!isq) {
        if (m == 0) wmax[wi] = rmax;
        __syncthreads();
        if (t == 0)
            partmax[rb] = fmaxf(fmaxf(wmax[0], wmax[1]), fmaxf(wmax[2], wmax[3]));
    }
}

// ---- 2b. reduce 25 partials -> kmax[bh] ----
__global__ __launch_bounds__(64) void kmax_kernel(
    const float* __restrict__ partmax, float* __restrict__ kmax)
{
    const int bh = blockIdx.x;
    const int t = threadIdx.x;
    float s = (t < 25) ? partmax[bh * 25 + t] : -1e30f;
    #pragma unroll
    for (int off = 1; off < 64; off <<= 1) s = fmaxf(s, __shfl_xor(s, off));
    if (t == 0) kmax[bh] = s;
}

// ---- 3. kvs partials: block = (bh, l-split, k-half). Thread owns (k, m8, d4).
//      kp transform (phi_k2) folded into staging. ----
__global__ __launch_bounds__(512) void kvs_kernel(
    const float* __restrict__ dd, const float* __restrict__ diagk,
    const float* __restrict__ kmax, const float* __restrict__ vb,
    const float* __restrict__ gum,
    float* __restrict__ kvspart, float* __restrict__ ksumpart)
{
    constexpr int TL = 64;
    __shared__ float kps[TL][64];
    __shared__ float vs[TL][32];
    __shared__ float egs[TL][8];
    const int bi = blockIdx.x;            // 64*3*2 = 384
    const int khalf = bi & 1;
    const int sp = (bi >> 1) % 3;
    const int bh = bi / 6;
    const int b = bh >> 3, h = bh & 7;
    const int lstart = (sp == 0) ? 0 : (sp == 1 ? 267 : 534);
    const int lend   = (sp == 0) ? 267 : (sp == 1 ? 534 : 800);
    const int t = threadIdx.x;
    const int kq = t >> 6;                // 0..7
    const int mg = (t >> 3) & 7;
    const int dg = t & 7;
    const float stab = kmax[bh];
    float acc[8][4];
    #pragma unroll
    for (int i = 0; i < 8; ++i)
        for (int j = 0; j < 4; ++j) acc[i][j] = 0.f;
    float sacc[8] = {0, 0, 0, 0, 0, 0, 0, 0};
    for (int l0 = lstart; l0 < lend; l0 += TL) {
        const int chunk = min(TL, lend - l0);
        __syncthreads();
        for (int j = t; j < chunk * 64; j += 512) {
            int ll = j >> 6, m = j & 63;
            int g = (b * L + l0 + ll) * 8 + h;
            kps[ll][m] = MINV * (expf(dd[g * 64 + m] - diagk[g] - stab) + 1e-6f);
        }
        for (int j = t; j < chunk * 32; j += 512) {
            int ll = j >> 5;
            vs[ll][j & 31] = vb[(b * L + l0 + ll) * 256 + h * 32 + (j & 31)];
        }
        for (int j = t; j < chunk * 8; j += 512) {
            int ll = j >> 3;
            egs[ll][j & 7] = expf(gum[((b * L + l0 + ll) * 8 + h) * 16 + khalf * 8 + (j & 7)]);
        }
        __syncthreads();
        #pragma unroll 2
        for (int ll = 0; ll < chunk; ++ll) {
            float egv = egs[ll][kq];
            const float4* kr = reinterpret_cast<const float4*>(&kps[ll][mg * 8]);
            float4 ka = kr[0], kb4 = kr[1];
            float4 v4 = *reinterpret_cast<const float4*>(&vs[ll][dg * 4]);
            float s[8];
            s[0] = ka.x * egv;  s[1] = ka.y * egv;  s[2] = ka.z * egv;  s[3] = ka.w * egv;
            s[4] = kb4.x * egv; s[5] = kb4.y * egv; s[6] = kb4.z * egv; s[7] = kb4.w * egv;
            #pragma unroll
            for (int mi = 0; mi < 8; ++mi) {
                acc[mi][0] += s[mi] * v4.x;
                acc[mi][1] += s[mi] * v4.y;
                acc[mi][2] += s[mi] * v4.z;
                acc[mi][3] += s[mi] * v4.w;
            }
            if (dg == 0) {
                #pragma unroll
                for (int mi = 0; mi < 8; ++mi) sacc[mi] += s[mi];
            }
        }
    }
    const int k = khalf * 8 + kq;
    float* kbase = kvspart + (((long)(sp * 64 + bh) * 16 + k) * 64 + mg * 8) * 32 + dg * 4;
    #pragma unroll
    for (int mi = 0; mi < 8; ++mi)
        *reinterpret_cast<float4*>(kbase + mi * 32) =
            make_float4(acc[mi][0], acc[mi][1], acc[mi][2], acc[mi][3]);
    if (dg == 0) {
        float* sb = ksumpart + ((long)(sp * 64 + bh) * 16 + k) * 64 + mg * 8;
        #pragma unroll
        for (int mi = 0; mi < 8; ++mi) sb[mi] = sacc[mi];
    }
}

// ---- 3b. reduce split partials ----
__global__ __launch_bounds__(256) void kvsreduce_kernel(
    const float* __restrict__ kvspart, const float* __restrict__ ksumpart,
    float* __restrict__ kvs, float* __restrict__ ksum)
{
    constexpr int NKVS4 = 2097152 / 4;    // 524288 float4
    constexpr int NKS = 65536;
    const int idx = blockIdx.x * 256 + threadIdx.x;
    if (idx < NKVS4) {
        const float4* p = reinterpret_cast<const float4*>(kvspart) + idx;
        float4 a = p[0], b4 = p[NKVS4], c = p[2 * NKVS4];
        reinterpret_cast<float4*>(kvs)[idx] =
            make_float4(a.x + b4.x + c.x, a.y + b4.y + c.y,
                        a.z + b4.z + c.z, a.w + b4.w + c.w);
    } else if (idx < NKVS4 + NKS) {
        int j = idx - NKVS4;
        ksum[j] = ksumpart[j] + ksumpart[NKS + j] + ksumpart[2 * NKS + j];
    }
}

// ---- 4. z = LN(mean_k (qp.kvs)*invden); den computed in-block from ksum ----
__global__ __launch_bounds__(320) void z_kernel(
    const float* __restrict__ qp, const float* __restrict__ kvs,
    const float* __restrict__ ksum, const float* __restrict__ ln_g,
    const float* __restrict__ ln_b, float* __restrict__ z)
{
    __shared__ float qps[80][64];     // 20 KB
    __shared__ float kvss[2048];      // 8 KB (one kk slice [64 m][32 d])
    __shared__ float ksums[16][64];   // 4 KB
    __shared__ float invden[80][16];  // 5 KB
    const int bi = blockIdx.x;        // 640
    const int bh = bi / 10;
    const int b = bh >> 3, h = bh & 7;
    const int l0 = (bi % 10) * 80;
    const int t = threadIdx.x;        // 320
    for (int j = t; j < 80 * 64; j += 320) {
        int ll = j >> 6;
        qps[ll][j & 63] = qp[((b * L + l0 + ll) * 8 + h) * 64 + (j & 63)];
    }
    for (int j = t; j < 16 * 64; j += 320)
        ksums[j >> 6][j & 63] = ksum[(long)bh * 1024 + j];
    __syncthreads();
    for (int j = t; j < 80 * 16; j += 320) {
        int ll = j >> 4, kk = j & 15;
        float s = 0.f;
        #pragma unroll 8
        for (int m = 0; m < 64; ++m) s += qps[ll][m] * ksums[kk][m];
        invden[ll][kk] = 1.0f / (s + 1e-8f);
    }
    const int lg = t >> 3;            // 0..39
    const int dg = t & 7;
    const int r0 = lg * 2, r1 = r0 + 1;
    float acc0[4] = {0, 0, 0, 0}, acc1[4] = {0, 0, 0, 0};
    for (int kk = 0; kk < 16; ++kk) {
        __syncthreads();
        const float4* src = reinterpret_cast<const float4*>(kvs + ((long)bh * 16 + kk) * 2048);
        for (int j = t; j < 512; j += 320)
            reinterpret_cast<float4*>(kvss)[j] = src[j];
        __syncthreads();
        float n0[4] = {0, 0, 0, 0}, n1[4] = {0, 0, 0, 0};
        #pragma unroll 4
        for (int m = 0; m < 64; ++m) {
            float4 k4 = *reinterpret_cast<const float4*>(&kvss[m * 32 + dg * 4]);
            float q0 = qps[r0][m], q1 = qps[r1][m];
            n0[0] += q0 * k4.x; n0[1] += q0 * k4.y; n0[2] += q0 * k4.z; n0[3] += q0 * k4.w;
            n1[0] += q1 * k4.x; n1[1] += q1 * k4.y; n1[2] += q1 * k4.z; n1[3] += q1 * k4.w;
        }
        float i0 = invden[r0][kk], i1 = invden[r1][kk];
        #pragma unroll
        for (int j = 0; j < 4; ++j) { acc0[j] += n0[j] * i0; acc1[j] += n1[j] * i1; }
    }
    const float4 g4 = reinterpret_cast<const float4*>(ln_g)[dg];
    const float4 b4 = reinterpret_cast<const float4*>(ln_b)[dg];
    #pragma unroll
    for (int ri = 0; ri < 2; ++ri) {
        float* a = ri ? acc1 : acc0;
        float zv[4];
        float s1 = 0.f, s2 = 0.f;
        #pragma unroll
        for (int j = 0; j < 4; ++j) {
            zv[j] = a[j] * (1.0f / 16.0f);
            s1 += zv[j]; s2 += zv[j] * zv[j];
        }
        #pragma unroll
        for (int off = 1; off < 8; off <<= 1) {
            s1 += __shfl_xor(s1, off);
            s2 += __shfl_xor(s2, off);
        }
        float mu = s1 * (1.0f / 32.0f);
        float var = s2 * (1.0f / 32.0f) - mu * mu;
        float rs = rsqrtf(var + 1e-5f);
        float4 o;
        o.x = (zv[0] - mu) * rs * g4.x + b4.x;
        o.y = (zv[1] - mu) * rs * g4.y + b4.y;
        o.z = (zv[2] - mu) * rs * g4.z + b4.z;
        o.w = (zv[3] - mu) * rs * g4.w + b4.w;
        const int r = ri ? r1 : r0;
        *reinterpret_cast<float4*>(&z[(b * L + l0 + r) * 256 + h * 32 + dg * 4]) = o;
    }
}

// ---- 6. h1 partials: split-K GEMM [512 x 10000] @ [10000 x 128] ----
__global__ __launch_bounds__(256) void adjfc_kernel(
    const float* __restrict__ adj, const float* __restrict__ fcw,
    float* __restrict__ h1part)
{
    __shared__ float fs[128 * 65];
    __shared__ float as[8][64];
    const int bi = blockIdx.x;        // 64 * ADJ_SPLIT
    const int bp = bi / ADJ_SPLIT;
    const int sp = bi % ADJ_SPLIT;
    const int b = bp >> 3, p = bp & 7;
    const int k0 = sp * ADJ_KC;
    const int kend = min(k0 + ADJ_KC, NN);
    const int t = threadIdx.x;
    const int c = t & 127, ph = t >> 7;
    float acc[4] = {0.f, 0.f, 0.f, 0.f};
    for (int j0 = k0; j0 < kend; j0 += 64) {
        const int len = min(64, kend - j0);
        for (int j = t; j < 128 * 64; j += 256) {
            int c2 = j >> 6, jj = j & 63;
            fs[c2 * 65 + jj] = (jj < len) ? fcw[(long)c2 * NN + j0 + jj] : 0.f;
        }
        for (int j = t; j < 8 * 64; j += 256) {
            int rr = j >> 6, jj = j & 63;
            as[rr][jj] = (jj < len) ? adj[((long)(b * 64 + p * 8 + rr)) * NN + j0 + jj] : 0.f;
        }
        __syncthreads();
        #pragma unroll 8
        for (int jj = 0; jj < 64; ++jj) {
            float wv = fs[c * 65 + jj];
            #pragma unroll
            for (int r4 = 0; r4 < 4; ++r4)
                acc[r4] += as[ph + r4 * 2][jj] * wv;
        }
        __syncthreads();
    }
    for (int r4 = 0; r4 < 4; ++r4) {
        int pl = ph + r4 * 2;
        h1part[((sp * 64 + bp) * 8 + pl) * 128 + c] = acc[r4];
    }
}

// ---- 7. w = softmax over patch_len; absorbs split-reduce + bias + relu ----
__global__ __launch_bounds__(128) void wsm_kernel(
    const float* __restrict__ h1part, const float* __restrict__ fcb,
    const float* __restrict__ ow, const float* __restrict__ ob,
    float* __restrict__ wsm)
{
    __shared__ float part[8][2];
    const int bp = blockIdx.x;
    const int t = threadIdx.x;   // 128
    float owv = ow[t], bb = fcb[t];
    for (int pl = 0; pl < 8; ++pl) {
        float h = 0.f;
        for (int s = 0; s < ADJ_SPLIT; ++s)
            h += h1part[((s * 64 + bp) * 8 + pl) * 128 + t];
        float v = fmaxf(h + bb, 0.f) * owv;
        #pragma unroll
        for (int off = 1; off < 64; off <<= 1) v += __shfl_xor(v, off);
        if ((t & 63) == 0) part[pl][t >> 6] = v;
    }
    __syncthreads();
    if (t == 0) {
        float lg[8], mx = -1e30f;
        for (int pl = 0; pl < 8; ++pl) {
            lg[pl] = part[pl][0] + part[pl][1] + ob[0];
            mx = fmaxf(mx, lg[pl]);
        }
        float s = 0.f;
        for (int pl = 0; pl < 8; ++pl) { lg[pl] = expf(lg[pl] - mx); s += lg[pl]; }
        for (int pl = 0; pl < 8; ++pl) wsm[bp * 8 + pl] = lg[pl] / s;
    }
}

// ---- 8. fused + row L1-normalize ----
__global__ __launch_bounds__(128) void fused_kernel(
    const float* __restrict__ adj, const float* __restrict__ wsm,
    float* __restrict__ fusedn)
{
    __shared__ float part[2];
    const int bi = blockIdx.x;        // (b*8+p)*100 + i
    const int b = bi / 800;
    const int p = (bi / 100) & 7;
    const int i = bi % 100;
    const int t = threadIdx.x;        // 128
    float f = 0.f;
    if (t < 100) {
        #pragma unroll
        for (int pl = 0; pl < 8; ++pl)
            f += adj[((long)(b * 64 + p * 8 + pl)) * NN + i * 100 + t] * wsm[(b * 8 + p) * 8 + pl];
    }
    float a = fabsf(f);
    #pragma unroll
    for (int off = 1; off < 64; off <<= 1) a += __shfl_xor(a, off);
    if ((t & 63) == 0) part[t >> 6] = a;
    __syncthreads();
    float denom = fmaxf(part[0] + part[1], 1e-12f);
    if (t < 100) fusedn[(long)bi * 100 + t] = f / denom;
}

// ---- 9. z += block-diag(fusedn) @ v  (10 rows per block) ----
__global__ __launch_bounds__(256) void bias_kernel(
    const float* __restrict__ fusedn, const float* __restrict__ vb,
    float* __restrict__ z)
{
    __shared__ float fs[10 * 100];
    const int bi = blockIdx.x;        // 64*10
    const int bp = bi / 10;
    const int b = bp >> 3, p = bp & 7;
    const int i0 = (bi % 10) * 10;
    const int t = threadIdx.x;
    for (int j = t; j < 1000; j += 256)
        fs[j] = fusedn[(long)bp * 10000 + i0 * 100 + j];
    __syncthreads();
    float acc[10];
    #pragma unroll
    for (int r = 0; r < 10; ++r) acc[r] = 0.f;
    for (int j = 0; j < 100; ++j) {
        float vj = vb[(b * 800 + p * 100 + j) * 256 + t];
        #pragma unroll
        for (int r = 0; r < 10; ++r)
            acc[r] += fs[r * 100 + j] * vj;
    }
    for (int r = 0; r < 10; ++r)
        z[(b * 800 + p * 100 + i0 + r) * 256 + t] += acc[r];
}

// ---- 10. out = zb @ Wo^T + bo (float4 weight loads) ----
__global__ __launch_bounds__(256) void out_kernel(
    const float* __restrict__ z, const float* __restrict__ Wo,
    const float* __restrict__ bo, float* __restrict__ out)
{
    __shared__ float zs[8][256];
    const int row0 = blockIdx.x * 8;
    const int t = threadIdx.x;
    for (int r = 0; r < 8; ++r) zs[r][t] = z[(row0 + r) * 256 + t];
    __syncthreads();
    float acc[8];
    #pragma unroll
    for (int r = 0; r < 8; ++r) acc[r] = 0.f;
    const float4* w4 = reinterpret_cast<const float4*>(Wo) + t * 64;
    for (int kk = 0; kk < 64; ++kk) {
        float4 wv = w4[kk];
        #pragma unroll
        for (int r = 0; r < 8; ++r) {
            const float* zr = &zs[r][kk * 4];
            acc[r] += zr[0] * wv.x + zr[1] * wv.y + zr[2] * wv.z + zr[3] * wv.w;
        }
    }
    float bb = bo[t];
    for (int r = 0; r < 8; ++r) out[(row0 + r) * 256 + t] = acc[r] + bb;
}

extern "C" void kernel_launch(void* const* d_in, const int* in_sizes, int n_in,
                              void* d_out, int out_size, void* d_ws, size_t ws_size,
                              hipStream_t stream) {
    const float* x     = (const float*)d_in[0];
    const float* adj   = (const float*)d_in[1];
    const float* Wq_w  = (const float*)d_in[2];
    const float* Wq_b  = (const float*)d_in[3];
    const float* Wk_w  = (const float*)d_in[4];
    const float* Wk_b  = (const float*)d_in[5];
    const float* Wv_w  = (const float*)d_in[6];
    const float* Wv_b  = (const float*)d_in[7];
    const float* Wo_w  = (const float*)d_in[8];
    const float* Wo_b  = (const float*)d_in[9];
    const float* ln_g  = (const float*)d_in[10];
    const float* ln_b  = (const float*)d_in[11];
    const float* fc_w  = (const float*)d_in[12];
    const float* fc_b  = (const float*)d_in[13];
    const float* out_w = (const float*)d_in[14];
    const float* out_b = (const float*)d_in[15];
    const float* proj  = (const float*)d_in[16];
    const float* gum   = (const float*)d_in[17];
    float* out = (float*)d_out;

    // ---- workspace layout (floats) ----
    // Region R (6,865,920 floats) is time-shared:
    //   early/late tenants: qbuf, kbuf (dead after phiqk), zbuf, h1part, fusedn
    //     (written only after kvsreduce)
    //   mid tenant: kvspart (6,291,456) + ksumpart (196,608) — live only
    //     between kvs_kernel and kvsreduce_kernel.
    float* ws = (float*)d_ws;
    float* qbuf    = ws;                      // 1,638,400
    float* kbuf    = qbuf + 1638400;          // 1,638,400
    float* zbuf    = kbuf + 1638400;          // 1,638,400
    float* h1part  = zbuf + 1638400;          // 1,310,720
    float* fusedn  = h1part + 1310720;        // 640,000   (R ends at 6,865,920)
    float* kvspart = ws;                      // 6,291,456 (overlay)
    float* ksumpart= ws + 6291456;            // 196,608   (overlay)
    float* after   = ws + 6865920;
    float* vbuf    = after;                   // 1,638,400
    float* qp      = vbuf + 1638400;          // 3,276,800
    float* kp      = qp + 3276800;            // 3,276,800 (raw dd for keys)
    float* diagk   = kp + 3276800;            // 51,200
    float* kvs     = diagk + 51200;           // 2,097,152
    float* ksum    = kvs + 2097152;           // 65,536
    float* wsm     = ksum + 65536;            // 512
    float* partmax = wsm + 512;               // 1,600
    float* kmax    = partmax + 1600;          // 64

    qkv_kernel<<<800, 256, 0, stream>>>(x, Wq_w, Wq_b, Wk_w, Wk_b, Wv_w, Wv_b,
                                        qbuf, kbuf, vbuf);
    phiqk_kernel<<<3200, 256, 0, stream>>>(qbuf, kbuf, proj, qp, kp, diagk, partmax);
    kmax_kernel<<<64, 64, 0, stream>>>(partmax, kmax);
    kvs_kernel<<<384, 512, 0, stream>>>(kp, diagk, kmax, vbuf, gum, kvspart, ksumpart);
    kvsreduce_kernel<<<2304, 256, 0, stream>>>(kvspart, ksumpart, kvs, ksum);
    z_kernel<<<640, 320, 0, stream>>>(qp, kvs, ksum, ln_g, ln_b, zbuf);
    adjfc_kernel<<<64 * ADJ_SPLIT, 256, 0, stream>>>(adj, fc_w, h1part);
    wsm_kernel<<<64, 128, 0, stream>>>(h1part, fc_b, out_w, out_b, wsm);
    fused_kernel<<<6400, 128, 0, stream>>>(adj, wsm, fusedn);
    bias_kernel<<<640, 256, 0, stream>>>(fusedn, vbuf, zbuf);
    out_kernel<<<800, 256, 0, stream>>>(zbuf, Wo_w, Wo_b, out);
}

// Round 5
// 561.864 us; speedup vs baseline: 3.0506x; 1.3293x over previous
//
#include <hip/hip_runtime.h>
#include <cstdint>

// ---- static config ----
constexpr int B = 8, P = 8, N = 100, D = 256, H = 8, DK = 32, M = 64, KG = 16;
constexpr int L = P * N;      // 800
constexpr int NN = N * N;     // 10000
constexpr float PHI_SCALE = 0.8408964152537145f;  // (1/sqrt(0.25)) * 32^-0.25
constexpr float MINV = 0.125f;                    // 64^-0.5
constexpr int ADJ_SPLIT = 8;                      // split-K for adjfc MFMA GEMM
constexpr int KPAD = 10240;                       // 10000 padded to 8*1280 (40*32)
constexpr int KVS_SPLIT = 3;                      // l-splits for kvs

typedef __attribute__((ext_vector_type(8))) short short8v;  // 8 bf16
typedef __attribute__((ext_vector_type(4))) float f32x4;

__device__ __forceinline__ unsigned short f2b(float f) {
    unsigned u = __float_as_uint(f);
    unsigned r = 0x7fffu + ((u >> 16) & 1u);
    return (unsigned short)((u + r) >> 16);
}

// ---- 0. convert adj & fc_w to bf16, K-padded to 10240 ----
__global__ __launch_bounds__(256) void convert_kernel(
    const float* __restrict__ adj, const float* __restrict__ fcw,
    unsigned short* __restrict__ adjb, unsigned short* __restrict__ fcwb)
{
    const int col = blockIdx.x * 256 + threadIdx.x;   // 0..10239
    const int row = blockIdx.y;                       // 0..639
    if (row < 512) {
        float v = (col < NN) ? adj[(long)row * NN + col] : 0.f;
        adjb[(long)row * KPAD + col] = f2b(v);
    } else {
        const int r = row - 512;
        float v = (col < NN) ? fcw[(long)r * NN + col] : 0.f;
        fcwb[(long)r * KPAD + col] = f2b(v);
    }
}

// ---- 1. adjfc via MFMA: h1part[sp][r][c] partial sums of flat@fcw^T ----
__global__ __launch_bounds__(256) void adjfc_mfma_kernel(
    const unsigned short* __restrict__ adjb, const unsigned short* __restrict__ fcwb,
    float* __restrict__ h1part)
{
    const int task = blockIdx.x * 4 + (threadIdx.x >> 6);  // 2048 tasks
    const int kt = task & 7;
    const int nt = (task >> 3) & 7;
    const int mt = task >> 6;            // 0..31
    const int lane = threadIdx.x & 63;
    const int row = lane & 15;
    const int ko = (lane >> 4) * 8;
    const unsigned short* pa = adjb + (long)(mt * 16 + row) * KPAD + kt * 1280 + ko;
    const unsigned short* pb = fcwb + (long)(nt * 16 + row) * KPAD + kt * 1280 + ko;
    f32x4 acc = {0.f, 0.f, 0.f, 0.f};
    #pragma unroll 4
    for (int s = 0; s < 40; ++s) {
        short8v a = *reinterpret_cast<const short8v*>(pa);
        short8v b = *reinterpret_cast<const short8v*>(pb);
        acc = __builtin_amdgcn_mfma_f32_16x16x32_bf16(a, b, acc, 0, 0, 0);
        pa += 32; pb += 32;
    }
    // C/D: col = lane&15, row = (lane>>4)*4 + j   [verified gfx950 mapping]
    const int c = nt * 16 + (lane & 15);
    const int rbase = mt * 16 + (lane >> 4) * 4;
    #pragma unroll
    for (int j = 0; j < 4; ++j) {
        int r = rbase + j;
        h1part[((long)kt * 512 + r) * 128 + c] = acc[j];
    }
}

// ---- 2. w = softmax over patch_len; absorbs split-reduce + bias + relu ----
__global__ __launch_bounds__(128) void wsm_kernel(
    const float* __restrict__ h1part, const float* __restrict__ fcb,
    const float* __restrict__ ow, const float* __restrict__ ob,
    float* __restrict__ wsm)
{
    __shared__ float part[8][2];
    const int bp = blockIdx.x;
    const int t = threadIdx.x;   // 128
    float owv = ow[t], bb = fcb[t];
    for (int pl = 0; pl < 8; ++pl) {
        float h = 0.f;
        for (int s = 0; s < ADJ_SPLIT; ++s)
            h += h1part[((long)s * 512 + bp * 8 + pl) * 128 + t];
        float v = fmaxf(h + bb, 0.f) * owv;
        #pragma unroll
        for (int off = 1; off < 64; off <<= 1) v += __shfl_xor(v, off);
        if ((t & 63) == 0) part[pl][t >> 6] = v;
    }
    __syncthreads();
    if (t == 0) {
        float lg[8], mx = -1e30f;
        for (int pl = 0; pl < 8; ++pl) {
            lg[pl] = part[pl][0] + part[pl][1] + ob[0];
            mx = fmaxf(mx, lg[pl]);
        }
        float s = 0.f;
        for (int pl = 0; pl < 8; ++pl) { lg[pl] = expf(lg[pl] - mx); s += lg[pl]; }
        for (int pl = 0; pl < 8; ++pl) wsm[bp * 8 + pl] = lg[pl] / s;
    }
}

// ---- 3. q,k,v GEMM: 64x64 tiles, LDS-staged transposed, 4x4 register tile ----
__global__ __launch_bounds__(256) void qkv_kernel(
    const float* __restrict__ x,
    const float* __restrict__ Wq, const float* __restrict__ bq,
    const float* __restrict__ Wk, const float* __restrict__ bk,
    const float* __restrict__ Wv, const float* __restrict__ bv,
    float* __restrict__ q, float* __restrict__ k, float* __restrict__ v)
{
    __shared__ __align__(16) float xs_t[64][68];
    __shared__ __align__(16) float ws_t[64][68];
    const int bi = blockIdx.x;            // 100 * 12
    const int mblk = bi % 100;
    const int nblk = bi / 100;
    const int row0 = mblk * 64;
    const int col0 = nblk * 64;           // global col in [0,768)
    const float* Wm; const float* bm; float* outp;
    if (col0 < 256)      { Wm = Wq; bm = bq; outp = q; }
    else if (col0 < 512) { Wm = Wk; bm = bk; outp = k; }
    else                 { Wm = Wv; bm = bv; outp = v; }
    const int ncol0 = col0 & 255;
    const int t = threadIdx.x;
    const int tr = t >> 4, tc = t & 15;
    float acc[4][4];
    #pragma unroll
    for (int i = 0; i < 4; ++i)
        for (int j = 0; j < 4; ++j) acc[i][j] = 0.f;
    for (int kc = 0; kc < 4; ++kc) {
        __syncthreads();
        #pragma unroll
        for (int i = 0; i < 16; ++i) {
            int j = t + i * 256;
            int r = j >> 6, kk = j & 63;
            xs_t[kk][r] = x[(long)(row0 + r) * 256 + kc * 64 + kk];
            ws_t[kk][r] = Wm[(long)(ncol0 + r) * 256 + kc * 64 + kk];
        }
        __syncthreads();
        #pragma unroll 8
        for (int kk = 0; kk < 64; ++kk) {
            float4 a4 = *reinterpret_cast<const float4*>(&xs_t[kk][tr * 4]);
            float4 b4 = *reinterpret_cast<const float4*>(&ws_t[kk][tc * 4]);
            float av[4] = {a4.x, a4.y, a4.z, a4.w};
            float bvv[4] = {b4.x, b4.y, b4.z, b4.w};
            #pragma unroll
            for (int i = 0; i < 4; ++i)
                #pragma unroll
                for (int j = 0; j < 4; ++j)
                    acc[i][j] += av[i] * bvv[j];
        }
    }
    float4 bias4 = *reinterpret_cast<const float4*>(&bm[ncol0 + tc * 4]);
    float bias[4] = {bias4.x, bias4.y, bias4.z, bias4.w};
    #pragma unroll
    for (int i = 0; i < 4; ++i) {
        float4 o;
        o.x = acc[i][0] + bias[0];
        o.y = acc[i][1] + bias[1];
        o.z = acc[i][2] + bias[2];
        o.w = acc[i][3] + bias[3];
        *reinterpret_cast<float4*>(&outp[(long)(row0 + tr * 4 + i) * 256 + ncol0 + tc * 4]) = o;
    }
}

// ---- 4. phi(q) and phi(k) pass1 in one kernel ----
__global__ __launch_bounds__(256) void phiqk_kernel(
    const float* __restrict__ qb, const float* __restrict__ kb,
    const float* __restrict__ proj,
    float* __restrict__ qp, float* __restrict__ ddout,
    float* __restrict__ diagout, float* __restrict__ partmax)
{
    __shared__ float ps[64 * 33];
    __shared__ float wmax[4];
    const int t = threadIdx.x;
    for (int j = t; j < 2048; j += 256) ps[(j >> 5) * 33 + (j & 31)] = proj[j];
    __syncthreads();
    const int bi = blockIdx.x;            // 3200: [0,1600) q, [1600,3200) k
    const bool isq = bi < 1600;
    const int rb = isq ? bi : bi - 1600;
    const int bh = rb / 25;
    const int b = bh >> 3, h = bh & 7;
    const int lbase = (rb % 25) * 32;
    const int wi = t >> 6;
    const int m = t & 63;
    const float* src = isq ? qb : kb;
    float rmax = -1e30f;
    for (int si = 0; si < 8; ++si) {
        const int l = lbase + si * 4 + wi;
        const float* ptr = src + (b * L + l) * 256 + h * 32;
        float dd = 0.f, diag = 0.f;
        #pragma unroll
        for (int d2 = 0; d2 < 32; ++d2) {
            float xv = ptr[d2] * PHI_SCALE;
            dd += xv * ps[m * 33 + d2];
            diag += xv * xv;
        }
        diag *= 0.5f;
        float s = dd;
        #pragma unroll
        for (int off = 1; off < 64; off <<= 1) s = fmaxf(s, __shfl_xor(s, off));
        const int group = (b * L + l) * 8 + h;
        if (isq) {
            qp[group * 64 + m] = MINV * (expf(dd - diag - s) + 1e-6f);
        } else {
            ddout[group * 64 + m] = dd;
            if (m == 0) diagout[group] = diag;
            rmax = fmaxf(rmax, s);
        }
    }
    if (!isq) {
        if (m == 0) wmax[wi] = rmax;
        __syncthreads();
        if (t == 0)
            partmax[rb] = fmaxf(fmaxf(wmax[0], wmax[1]), fmaxf(wmax[2], wmax[3]));
    }
}

// ---- 4b. reduce 25 partials -> kmax[bh] ----
__global__ __launch_bounds__(64) void kmax_kernel(
    const float* __restrict__ partmax, float* __restrict__ kmax)
{
    const int bh = blockIdx.x;
    const int t = threadIdx.x;
    float s = (t < 25) ? partmax[bh * 25 + t] : -1e30f;
    #pragma unroll
    for (int off = 1; off < 64; off <<= 1) s = fmaxf(s, __shfl_xor(s, off));
    if (t == 0) kmax[bh] = s;
}

// ---- 5. kvs partials ----
__global__ __launch_bounds__(512) void kvs_kernel(
    const float* __restrict__ dd, const float* __restrict__ diagk,
    const float* __restrict__ kmax, const float* __restrict__ vb,
    const float* __restrict__ gum,
    float* __restrict__ kvspart, float* __restrict__ ksumpart)
{
    constexpr int TL = 64;
    __shared__ float kps[TL][64];
    __shared__ float vs[TL][32];
    __shared__ float egs[TL][8];
    const int bi = blockIdx.x;            // 384
    const int khalf = bi & 1;
    const int sp = (bi >> 1) % 3;
    const int bh = bi / 6;
    const int b = bh >> 3, h = bh & 7;
    const int lstart = (sp == 0) ? 0 : (sp == 1 ? 267 : 534);
    const int lend   = (sp == 0) ? 267 : (sp == 1 ? 534 : 800);
    const int t = threadIdx.x;
    const int kq = t >> 6;
    const int mg = (t >> 3) & 7;
    const int dg = t & 7;
    const float stab = kmax[bh];
    float acc[8][4];
    #pragma unroll
    for (int i = 0; i < 8; ++i)
        for (int j = 0; j < 4; ++j) acc[i][j] = 0.f;
    float sacc[8] = {0, 0, 0, 0, 0, 0, 0, 0};
    for (int l0 = lstart; l0 < lend; l0 += TL) {
        const int chunk = min(TL, lend - l0);
        __syncthreads();
        for (int j = t; j < chunk * 64; j += 512) {
            int ll = j >> 6, m = j & 63;
            int g = (b * L + l0 + ll) * 8 + h;
            kps[ll][m] = MINV * (expf(dd[g * 64 + m] - diagk[g] - stab) + 1e-6f);
        }
        for (int j = t; j < chunk * 32; j += 512) {
            int ll = j >> 5;
            vs[ll][j & 31] = vb[(b * L + l0 + ll) * 256 + h * 32 + (j & 31)];
        }
        for (int j = t; j < chunk * 8; j += 512) {
            int ll = j >> 3;
            egs[ll][j & 7] = expf(gum[((b * L + l0 + ll) * 8 + h) * 16 + khalf * 8 + (j & 7)]);
        }
        __syncthreads();
        #pragma unroll 2
        for (int ll = 0; ll < chunk; ++ll) {
            float egv = egs[ll][kq];
            const float4* kr = reinterpret_cast<const float4*>(&kps[ll][mg * 8]);
            float4 ka = kr[0], kb4 = kr[1];
            float4 v4 = *reinterpret_cast<const float4*>(&vs[ll][dg * 4]);
            float s[8];
            s[0] = ka.x * egv;  s[1] = ka.y * egv;  s[2] = ka.z * egv;  s[3] = ka.w * egv;
            s[4] = kb4.x * egv; s[5] = kb4.y * egv; s[6] = kb4.z * egv; s[7] = kb4.w * egv;
            #pragma unroll
            for (int mi = 0; mi < 8; ++mi) {
                acc[mi][0] += s[mi] * v4.x;
                acc[mi][1] += s[mi] * v4.y;
                acc[mi][2] += s[mi] * v4.z;
                acc[mi][3] += s[mi] * v4.w;
            }
            if (dg == 0) {
                #pragma unroll
                for (int mi = 0; mi < 8; ++mi) sacc[mi] += s[mi];
            }
        }
    }
    const int k = khalf * 8 + kq;
    float* kbase = kvspart + (((long)(sp * 64 + bh) * 16 + k) * 64 + mg * 8) * 32 + dg * 4;
    #pragma unroll
    for (int mi = 0; mi < 8; ++mi)
        *reinterpret_cast<float4*>(kbase + mi * 32) =
            make_float4(acc[mi][0], acc[mi][1], acc[mi][2], acc[mi][3]);
    if (dg == 0) {
        float* sb = ksumpart + ((long)(sp * 64 + bh) * 16 + k) * 64 + mg * 8;
        #pragma unroll
        for (int mi = 0; mi < 8; ++mi) sb[mi] = sacc[mi];
    }
}

// ---- 5b. reduce split partials ----
__global__ __launch_bounds__(256) void kvsreduce_kernel(
    const float* __restrict__ kvspart, const float* __restrict__ ksumpart,
    float* __restrict__ kvs, float* __restrict__ ksum)
{
    constexpr int NKVS4 = 2097152 / 4;
    constexpr int NKS = 65536;
    const int idx = blockIdx.x * 256 + threadIdx.x;
    if (idx < NKVS4) {
        const float4* p = reinterpret_cast<const float4*>(kvspart) + idx;
        float4 a = p[0], b4 = p[NKVS4], c = p[2 * NKVS4];
        reinterpret_cast<float4*>(kvs)[idx] =
            make_float4(a.x + b4.x + c.x, a.y + b4.y + c.y,
                        a.z + b4.z + c.z, a.w + b4.w + c.w);
    } else if (idx < NKVS4 + NKS) {
        int j = idx - NKVS4;
        ksum[j] = ksumpart[j] + ksumpart[NKS + j] + ksumpart[2 * NKS + j];
    }
}

// ---- 6. z = LN(mean_k (qp.kvs)*invden) ----
__global__ __launch_bounds__(320) void z_kernel(
    const float* __restrict__ qp, const float* __restrict__ kvs,
    const float* __restrict__ ksum, const float* __restrict__ ln_g,
    const float* __restrict__ ln_b, float* __restrict__ z)
{
    __shared__ float qps[80][64];
    __shared__ float kvss[2048];
    __shared__ float ksums[16][64];
    __shared__ float invden[80][16];
    const int bi = blockIdx.x;        // 640
    const int bh = bi / 10;
    const int b = bh >> 3, h = bh & 7;
    const int l0 = (bi % 10) * 80;
    const int t = threadIdx.x;        // 320
    for (int j = t; j < 80 * 64; j += 320) {
        int ll = j >> 6;
        qps[ll][j & 63] = qp[((b * L + l0 + ll) * 8 + h) * 64 + (j & 63)];
    }
    for (int j = t; j < 16 * 64; j += 320)
        ksums[j >> 6][j & 63] = ksum[(long)bh * 1024 + j];
    __syncthreads();
    for (int j = t; j < 80 * 16; j += 320) {
        int ll = j >> 4, kk = j & 15;
        float s = 0.f;
        #pragma unroll 8
        for (int m = 0; m < 64; ++m) s += qps[ll][m] * ksums[kk][m];
        invden[ll][kk] = 1.0f / (s + 1e-8f);
    }
    const int lg = t >> 3;
    const int dg = t & 7;
    const int r0 = lg * 2, r1 = r0 + 1;
    float acc0[4] = {0, 0, 0, 0}, acc1[4] = {0, 0, 0, 0};
    for (int kk = 0; kk < 16; ++kk) {
        __syncthreads();
        const float4* src = reinterpret_cast<const float4*>(kvs + ((long)bh * 16 + kk) * 2048);
        for (int j = t; j < 512; j += 320)
            reinterpret_cast<float4*>(kvss)[j] = src[j];
        __syncthreads();
        float n0[4] = {0, 0, 0, 0}, n1[4] = {0, 0, 0, 0};
        #pragma unroll 4
        for (int m = 0; m < 64; ++m) {
            float4 k4 = *reinterpret_cast<const float4*>(&kvss[m * 32 + dg * 4]);
            float q0 = qps[r0][m], q1 = qps[r1][m];
            n0[0] += q0 * k4.x; n0[1] += q0 * k4.y; n0[2] += q0 * k4.z; n0[3] += q0 * k4.w;
            n1[0] += q1 * k4.x; n1[1] += q1 * k4.y; n1[2] += q1 * k4.z; n1[3] += q1 * k4.w;
        }
        float i0 = invden[r0][kk], i1 = invden[r1][kk];
        #pragma unroll
        for (int j = 0; j < 4; ++j) { acc0[j] += n0[j] * i0; acc1[j] += n1[j] * i1; }
    }
    const float4 g4 = reinterpret_cast<const float4*>(ln_g)[dg];
    const float4 b4 = reinterpret_cast<const float4*>(ln_b)[dg];
    #pragma unroll
    for (int ri = 0; ri < 2; ++ri) {
        float* a = ri ? acc1 : acc0;
        float zv[4];
        float s1 = 0.f, s2 = 0.f;
        #pragma unroll
        for (int j = 0; j < 4; ++j) {
            zv[j] = a[j] * (1.0f / 16.0f);
            s1 += zv[j]; s2 += zv[j] * zv[j];
        }
        #pragma unroll
        for (int off = 1; off < 8; off <<= 1) {
            s1 += __shfl_xor(s1, off);
            s2 += __shfl_xor(s2, off);
        }
        float mu = s1 * (1.0f / 32.0f);
        float var = s2 * (1.0f / 32.0f) - mu * mu;
        float rs = rsqrtf(var + 1e-5f);
        float4 o;
        o.x = (zv[0] - mu) * rs * g4.x + b4.x;
        o.y = (zv[1] - mu) * rs * g4.y + b4.y;
        o.z = (zv[2] - mu) * rs * g4.z + b4.z;
        o.w = (zv[3] - mu) * rs * g4.w + b4.w;
        const int r = ri ? r1 : r0;
        *reinterpret_cast<float4*>(&z[(b * L + l0 + r) * 256 + h * 32 + dg * 4]) = o;
    }
}

// ---- 7. fused + row L1-normalize ----
__global__ __launch_bounds__(128) void fused_kernel(
    const float* __restrict__ adj, const float* __restrict__ wsm,
    float* __restrict__ fusedn)
{
    __shared__ float part[2];
    const int bi = blockIdx.x;
    const int b = bi / 800;
    const int p = (bi / 100) & 7;
    const int i = bi % 100;
    const int t = threadIdx.x;
    float f = 0.f;
    if (t < 100) {
        #pragma unroll
        for (int pl = 0; pl < 8; ++pl)
            f += adj[((long)(b * 64 + p * 8 + pl)) * NN + i * 100 + t] * wsm[(b * 8 + p) * 8 + pl];
    }
    float a = fabsf(f);
    #pragma unroll
    for (int off = 1; off < 64; off <<= 1) a += __shfl_xor(a, off);
    if ((t & 63) == 0) part[t >> 6] = a;
    __syncthreads();
    float denom = fmaxf(part[0] + part[1], 1e-12f);
    if (t < 100) fusedn[(long)bi * 100 + t] = f / denom;
}

// ---- 8. z += block-diag(fusedn) @ v ----
__global__ __launch_bounds__(256) void bias_kernel(
    const float* __restrict__ fusedn, const float* __restrict__ vb,
    float* __restrict__ z)
{
    __shared__ float fs[10 * 100];
    const int bi = blockIdx.x;
    const int bp = bi / 10;
    const int b = bp >> 3, p = bp & 7;
    const int i0 = (bi % 10) * 10;
    const int t = threadIdx.x;
    for (int j = t; j < 1000; j += 256)
        fs[j] = fusedn[(long)bp * 10000 + i0 * 100 + j];
    __syncthreads();
    float acc[10];
    #pragma unroll
    for (int r = 0; r < 10; ++r) acc[r] = 0.f;
    for (int j = 0; j < 100; ++j) {
        float vj = vb[(b * 800 + p * 100 + j) * 256 + t];
        #pragma unroll
        for (int r = 0; r < 10; ++r)
            acc[r] += fs[r * 100 + j] * vj;
    }
    for (int r = 0; r < 10; ++r)
        z[(b * 800 + p * 100 + i0 + r) * 256 + t] += acc[r];
}

// ---- 9. out = zb @ Wo^T + bo ----
__global__ __launch_bounds__(256) void out_kernel(
    const float* __restrict__ z, const float* __restrict__ Wo,
    const float* __restrict__ bo, float* __restrict__ out)
{
    __shared__ float zs[8][256];
    const int row0 = blockIdx.x * 8;
    const int t = threadIdx.x;
    for (int r = 0; r < 8; ++r) zs[r][t] = z[(row0 + r) * 256 + t];
    __syncthreads();
    float acc[8];
    #pragma unroll
    for (int r = 0; r < 8; ++r) acc[r] = 0.f;
    const float4* w4 = reinterpret_cast<const float4*>(Wo) + t * 64;
    for (int kk = 0; kk < 64; ++kk) {
        float4 wv = w4[kk];
        #pragma unroll
        for (int r = 0; r < 8; ++r) {
            const float* zr = &zs[r][kk * 4];
            acc[r] += zr[0] * wv.x + zr[1] * wv.y + zr[2] * wv.z + zr[3] * wv.w;
        }
    }
    float bb = bo[t];
    for (int r = 0; r < 8; ++r) out[(row0 + r) * 256 + t] = acc[r] + bb;
}

extern "C" void kernel_launch(void* const* d_in, const int* in_sizes, int n_in,
                              void* d_out, int out_size, void* d_ws, size_t ws_size,
                              hipStream_t stream) {
    const float* x     = (const float*)d_in[0];
    const float* adj   = (const float*)d_in[1];
    const float* Wq_w  = (const float*)d_in[2];
    const float* Wq_b  = (const float*)d_in[3];
    const float* Wk_w  = (const float*)d_in[4];
    const float* Wk_b  = (const float*)d_in[5];
    const float* Wv_w  = (const float*)d_in[6];
    const float* Wv_b  = (const float*)d_in[7];
    const float* Wo_w  = (const float*)d_in[8];
    const float* Wo_b  = (const float*)d_in[9];
    const float* ln_g  = (const float*)d_in[10];
    const float* ln_b  = (const float*)d_in[11];
    const float* fc_w  = (const float*)d_in[12];
    const float* fc_b  = (const float*)d_in[13];
    const float* out_w = (const float*)d_in[14];
    const float* out_b = (const float*)d_in[15];
    const float* proj  = (const float*)d_in[16];
    const float* gum   = (const float*)d_in[17];
    float* out = (float*)d_out;

    // ---- workspace layout (float units) ----
    // Overlay region [0, 6,488,064) time-shared by disjoint-lifetime tenants:
    //  t1 (convert->wsm):   adjb 2,621,440 | fcwb 655,360 | h1part 524,288  (3,801,088)
    //  t2 (qkv->phiqk):     qbuf 1,638,400 | kbuf 1,638,400                 (3,276,800)
    //  t3 (kvs->kvsreduce): kvspart 6,291,456 | ksumpart 196,608            (6,488,064)
    //  t4 (z->out):         zbuf 1,638,400 | fusedn 640,000                 (2,278,400)
    float* ws = (float*)d_ws;
    float* ovl = ws;
    unsigned short* adjb = (unsigned short*)ovl;              // 512*10240 bf16
    unsigned short* fcwb = (unsigned short*)(ovl + 2621440);  // 128*10240 bf16
    float* h1part  = ovl + 3276800;     // 524,288
    float* qbuf    = ovl;               // 1,638,400
    float* kbuf    = ovl + 1638400;     // 1,638,400
    float* kvspart = ovl;               // 6,291,456
    float* ksumpart= ovl + 6291456;     // 196,608
    float* zbuf    = ovl;               // 1,638,400
    float* fusedn  = ovl + 1638400;     // 640,000
    float* after   = ws + 6488064;
    float* vbuf    = after;             // 1,638,400
    float* qp      = vbuf + 1638400;    // 3,276,800
    float* kp      = qp + 3276800;      // 3,276,800 (raw dd for keys)
    float* diagk   = kp + 3276800;      // 51,200
    float* kvs     = diagk + 51200;     // 2,097,152
    float* ksum    = kvs + 2097152;     // 65,536
    float* wsm     = ksum + 65536;      // 512
    float* partmax = wsm + 512;         // 1,600
    float* kmax    = partmax + 1600;    // 64

    // adj path first so t1 tenants die before qkv
    convert_kernel<<<dim3(40, 640), 256, 0, stream>>>(adj, fc_w, adjb, fcwb);
    adjfc_mfma_kernel<<<512, 256, 0, stream>>>(adjb, fcwb, h1part);
    wsm_kernel<<<64, 128, 0, stream>>>(h1part, fc_b, out_w, out_b, wsm);

    qkv_kernel<<<1200, 256, 0, stream>>>(x, Wq_w, Wq_b, Wk_w, Wk_b, Wv_w, Wv_b,
                                         qbuf, kbuf, vbuf);
    phiqk_kernel<<<3200, 256, 0, stream>>>(qbuf, kbuf, proj, qp, kp, diagk, partmax);
    kmax_kernel<<<64, 64, 0, stream>>>(partmax, kmax);
    kvs_kernel<<<384, 512, 0, stream>>>(kp, diagk, kmax, vbuf, gum, kvspart, ksumpart);
    kvsreduce_kernel<<<2304, 256, 0, stream>>>(kvspart, ksumpart, kvs, ksum);
    z_kernel<<<640, 320, 0, stream>>>(qp, kvs, ksum, ln_g, ln_b, zbuf);
    fused_kernel<<<6400, 128, 0, stream>>>(adj, wsm, fusedn);
    bias_kernel<<<640, 256, 0, stream>>>(fusedn, vbuf, zbuf);
    out_kernel<<<800, 256, 0, stream>>>(zbuf, Wo_w, Wo_b, out);
}

// Round 6
// 532.922 us; speedup vs baseline: 3.2163x; 1.0543x over previous
//
#include <hip/hip_runtime.h>
#include <cstdint>

// ---- static config ----
constexpr int B = 8, P = 8, N = 100, D = 256, H = 8, DK = 32, M = 64, KG = 16;
constexpr int L = P * N;      // 800
constexpr int NN = N * N;     // 10000
constexpr float PHI_SCALE = 0.8408964152537145f;  // (1/sqrt(0.25)) * 32^-0.25
constexpr float MINV = 0.125f;                    // 64^-0.5
constexpr int ADJ_SPLIT = 8;                      // split-K for adjfc MFMA GEMM
constexpr int KPAD = 10240;                       // 10000 padded to 8*1280 (40*32)
constexpr int KVS_SPLIT = 3;                      // l-splits for kvs

typedef __attribute__((ext_vector_type(8))) short short8v;  // 8 bf16
typedef __attribute__((ext_vector_type(4))) float f32x4;

__device__ __forceinline__ unsigned short f2b(float f) {
    unsigned u = __float_as_uint(f);
    unsigned r = 0x7fffu + ((u >> 16) & 1u);
    return (unsigned short)((u + r) >> 16);
}

// ---- 0. convert adj & fc_w to bf16, K-padded to 10240 ----
__global__ __launch_bounds__(256) void convert_kernel(
    const float* __restrict__ adj, const float* __restrict__ fcw,
    unsigned short* __restrict__ adjb, unsigned short* __restrict__ fcwb)
{
    const int col = blockIdx.x * 256 + threadIdx.x;   // 0..10239
    const int row = blockIdx.y;                       // 0..639
    if (row < 512) {
        float v = (col < NN) ? adj[(long)row * NN + col] : 0.f;
        adjb[(long)row * KPAD + col] = f2b(v);
    } else {
        const int r = row - 512;
        float v = (col < NN) ? fcw[(long)r * NN + col] : 0.f;
        fcwb[(long)r * KPAD + col] = f2b(v);
    }
}

// ---- 1. adjfc via MFMA: h1part[sp][r][c] partial sums of flat@fcw^T ----
__global__ __launch_bounds__(256) void adjfc_mfma_kernel(
    const unsigned short* __restrict__ adjb, const unsigned short* __restrict__ fcwb,
    float* __restrict__ h1part)
{
    const int task = blockIdx.x * 4 + (threadIdx.x >> 6);  // 2048 tasks
    const int kt = task & 7;
    const int nt = (task >> 3) & 7;
    const int mt = task >> 6;            // 0..31
    const int lane = threadIdx.x & 63;
    const int row = lane & 15;
    const int ko = (lane >> 4) * 8;
    const unsigned short* pa = adjb + (long)(mt * 16 + row) * KPAD + kt * 1280 + ko;
    const unsigned short* pb = fcwb + (long)(nt * 16 + row) * KPAD + kt * 1280 + ko;
    f32x4 acc = {0.f, 0.f, 0.f, 0.f};
    #pragma unroll 4
    for (int s = 0; s < 40; ++s) {
        short8v a = *reinterpret_cast<const short8v*>(pa);
        short8v b = *reinterpret_cast<const short8v*>(pb);
        acc = __builtin_amdgcn_mfma_f32_16x16x32_bf16(a, b, acc, 0, 0, 0);
        pa += 32; pb += 32;
    }
    const int c = nt * 16 + (lane & 15);
    const int rbase = mt * 16 + (lane >> 4) * 4;
    #pragma unroll
    for (int j = 0; j < 4; ++j) {
        int r = rbase + j;
        h1part[((long)kt * 512 + r) * 128 + c] = acc[j];
    }
}

// ---- 2. w = softmax over patch_len; absorbs split-reduce + bias + relu ----
__global__ __launch_bounds__(128) void wsm_kernel(
    const float* __restrict__ h1part, const float* __restrict__ fcb,
    const float* __restrict__ ow, const float* __restrict__ ob,
    float* __restrict__ wsm)
{
    __shared__ float part[8][2];
    const int bp = blockIdx.x;
    const int t = threadIdx.x;   // 128
    float owv = ow[t], bb = fcb[t];
    for (int pl = 0; pl < 8; ++pl) {
        float h = 0.f;
        for (int s = 0; s < ADJ_SPLIT; ++s)
            h += h1part[((long)s * 512 + bp * 8 + pl) * 128 + t];
        float v = fmaxf(h + bb, 0.f) * owv;
        #pragma unroll
        for (int off = 1; off < 64; off <<= 1) v += __shfl_xor(v, off);
        if ((t & 63) == 0) part[pl][t >> 6] = v;
    }
    __syncthreads();
    if (t == 0) {
        float lg[8], mx = -1e30f;
        for (int pl = 0; pl < 8; ++pl) {
            lg[pl] = part[pl][0] + part[pl][1] + ob[0];
            mx = fmaxf(mx, lg[pl]);
        }
        float s = 0.f;
        for (int pl = 0; pl < 8; ++pl) { lg[pl] = expf(lg[pl] - mx); s += lg[pl]; }
        for (int pl = 0; pl < 8; ++pl) wsm[bp * 8 + pl] = lg[pl] / s;
    }
}

// ---- 3. q,k,v GEMM: 64x64 tiles, LDS-staged transposed, 4x4 register tile ----
__global__ __launch_bounds__(256) void qkv_kernel(
    const float* __restrict__ x,
    const float* __restrict__ Wq, const float* __restrict__ bq,
    const float* __restrict__ Wk, const float* __restrict__ bk,
    const float* __restrict__ Wv, const float* __restrict__ bv,
    float* __restrict__ q, float* __restrict__ k, float* __restrict__ v)
{
    __shared__ __align__(16) float xs_t[64][68];
    __shared__ __align__(16) float ws_t[64][68];
    const int bi = blockIdx.x;            // 100 * 12
    const int mblk = bi % 100;
    const int nblk = bi / 100;
    const int row0 = mblk * 64;
    const int col0 = nblk * 64;           // global col in [0,768)
    const float* Wm; const float* bm; float* outp;
    if (col0 < 256)      { Wm = Wq; bm = bq; outp = q; }
    else if (col0 < 512) { Wm = Wk; bm = bk; outp = k; }
    else                 { Wm = Wv; bm = bv; outp = v; }
    const int ncol0 = col0 & 255;
    const int t = threadIdx.x;
    const int tr = t >> 4, tc = t & 15;
    float acc[4][4];
    #pragma unroll
    for (int i = 0; i < 4; ++i)
        for (int j = 0; j < 4; ++j) acc[i][j] = 0.f;
    for (int kc = 0; kc < 4; ++kc) {
        __syncthreads();
        #pragma unroll
        for (int i = 0; i < 16; ++i) {
            int j = t + i * 256;
            int r = j >> 6, kk = j & 63;
            xs_t[kk][r] = x[(long)(row0 + r) * 256 + kc * 64 + kk];
            ws_t[kk][r] = Wm[(long)(ncol0 + r) * 256 + kc * 64 + kk];
        }
        __syncthreads();
        #pragma unroll 8
        for (int kk = 0; kk < 64; ++kk) {
            float4 a4 = *reinterpret_cast<const float4*>(&xs_t[kk][tr * 4]);
            float4 b4 = *reinterpret_cast<const float4*>(&ws_t[kk][tc * 4]);
            float av[4] = {a4.x, a4.y, a4.z, a4.w};
            float bvv[4] = {b4.x, b4.y, b4.z, b4.w};
            #pragma unroll
            for (int i = 0; i < 4; ++i)
                #pragma unroll
                for (int j = 0; j < 4; ++j)
                    acc[i][j] += av[i] * bvv[j];
        }
    }
    float4 bias4 = *reinterpret_cast<const float4*>(&bm[ncol0 + tc * 4]);
    float bias[4] = {bias4.x, bias4.y, bias4.z, bias4.w};
    #pragma unroll
    for (int i = 0; i < 4; ++i) {
        float4 o;
        o.x = acc[i][0] + bias[0];
        o.y = acc[i][1] + bias[1];
        o.z = acc[i][2] + bias[2];
        o.w = acc[i][3] + bias[3];
        *reinterpret_cast<float4*>(&outp[(long)(row0 + tr * 4 + i) * 256 + ncol0 + tc * 4]) = o;
    }
}

// ---- 4. phi(q) and phi(k) pass1 in one kernel ----
__global__ __launch_bounds__(256) void phiqk_kernel(
    const float* __restrict__ qb, const float* __restrict__ kb,
    const float* __restrict__ proj,
    float* __restrict__ qp, float* __restrict__ ddout,
    float* __restrict__ diagout, float* __restrict__ partmax)
{
    __shared__ float ps[64 * 33];
    __shared__ float wmax[4];
    const int t = threadIdx.x;
    for (int j = t; j < 2048; j += 256) ps[(j >> 5) * 33 + (j & 31)] = proj[j];
    __syncthreads();
    const int bi = blockIdx.x;            // 3200: [0,1600) q, [1600,3200) k
    const bool isq = bi < 1600;
    const int rb = isq ? bi : bi - 1600;
    const int bh = rb / 25;
    const int b = bh >> 3, h = bh & 7;
    const int lbase = (rb % 25) * 32;
    const int wi = t >> 6;
    const int m = t & 63;
    const float* src = isq ? qb : kb;
    float rmax = -1e30f;
    for (int si = 0; si < 8; ++si) {
        const int l = lbase + si * 4 + wi;
        const float* ptr = src + (b * L + l) * 256 + h * 32;
        float dd = 0.f, diag = 0.f;
        #pragma unroll
        for (int d2 = 0; d2 < 32; ++d2) {
            float xv = ptr[d2] * PHI_SCALE;
            dd += xv * ps[m * 33 + d2];
            diag += xv * xv;
        }
        diag *= 0.5f;
        float s = dd;
        #pragma unroll
        for (int off = 1; off < 64; off <<= 1) s = fmaxf(s, __shfl_xor(s, off));
        const int group = (b * L + l) * 8 + h;
        if (isq) {
            qp[group * 64 + m] = MINV * (expf(dd - diag - s) + 1e-6f);
        } else {
            ddout[group * 64 + m] = dd;
            if (m == 0) diagout[group] = diag;
            rmax = fmaxf(rmax, s);
        }
    }
    if (!isq) {
        if (m == 0) wmax[wi] = rmax;
        __syncthreads();
        if (t == 0)
            partmax[rb] = fmaxf(fmaxf(wmax[0], wmax[1]), fmaxf(wmax[2], wmax[3]));
    }
}

// ---- 4b. reduce 25 partials -> kmax[bh] ----
__global__ __launch_bounds__(64) void kmax_kernel(
    const float* __restrict__ partmax, float* __restrict__ kmax)
{
    const int bh = blockIdx.x;
    const int t = threadIdx.x;
    float s = (t < 25) ? partmax[bh * 25 + t] : -1e30f;
    #pragma unroll
    for (int off = 1; off < 64; off <<= 1) s = fmaxf(s, __shfl_xor(s, off));
    if (t == 0) kmax[bh] = s;
}

// ---- 5. kvs partials ----
__global__ __launch_bounds__(512) void kvs_kernel(
    const float* __restrict__ dd, const float* __restrict__ diagk,
    const float* __restrict__ kmax, const float* __restrict__ vb,
    const float* __restrict__ gum,
    float* __restrict__ kvspart, float* __restrict__ ksumpart)
{
    constexpr int TL = 64;
    __shared__ float kps[TL][64];
    __shared__ float vs[TL][32];
    __shared__ float egs[TL][8];
    const int bi = blockIdx.x;            // 384
    const int khalf = bi & 1;
    const int sp = (bi >> 1) % 3;
    const int bh = bi / 6;
    const int b = bh >> 3, h = bh & 7;
    const int lstart = (sp == 0) ? 0 : (sp == 1 ? 267 : 534);
    const int lend   = (sp == 0) ? 267 : (sp == 1 ? 534 : 800);
    const int t = threadIdx.x;
    const int kq = t >> 6;
    const int mg = (t >> 3) & 7;
    const int dg = t & 7;
    const float stab = kmax[bh];
    float acc[8][4];
    #pragma unroll
    for (int i = 0; i < 8; ++i)
        for (int j = 0; j < 4; ++j) acc[i][j] = 0.f;
    float sacc[8] = {0, 0, 0, 0, 0, 0, 0, 0};
    for (int l0 = lstart; l0 < lend; l0 += TL) {
        const int chunk = min(TL, lend - l0);
        __syncthreads();
        for (int j = t; j < chunk * 64; j += 512) {
            int ll = j >> 6, m = j & 63;
            int g = (b * L + l0 + ll) * 8 + h;
            kps[ll][m] = MINV * (expf(dd[g * 64 + m] - diagk[g] - stab) + 1e-6f);
        }
        for (int j = t; j < chunk * 32; j += 512) {
            int ll = j >> 5;
            vs[ll][j & 31] = vb[(b * L + l0 + ll) * 256 + h * 32 + (j & 31)];
        }
        for (int j = t; j < chunk * 8; j += 512) {
            int ll = j >> 3;
            egs[ll][j & 7] = expf(gum[((b * L + l0 + ll) * 8 + h) * 16 + khalf * 8 + (j & 7)]);
        }
        __syncthreads();
        #pragma unroll 2
        for (int ll = 0; ll < chunk; ++ll) {
            float egv = egs[ll][kq];
            const float4* kr = reinterpret_cast<const float4*>(&kps[ll][mg * 8]);
            float4 ka = kr[0], kb4 = kr[1];
            float4 v4 = *reinterpret_cast<const float4*>(&vs[ll][dg * 4]);
            float s[8];
            s[0] = ka.x * egv;  s[1] = ka.y * egv;  s[2] = ka.z * egv;  s[3] = ka.w * egv;
            s[4] = kb4.x * egv; s[5] = kb4.y * egv; s[6] = kb4.z * egv; s[7] = kb4.w * egv;
            #pragma unroll
            for (int mi = 0; mi < 8; ++mi) {
                acc[mi][0] += s[mi] * v4.x;
                acc[mi][1] += s[mi] * v4.y;
                acc[mi][2] += s[mi] * v4.z;
                acc[mi][3] += s[mi] * v4.w;
            }
            if (dg == 0) {
                #pragma unroll
                for (int mi = 0; mi < 8; ++mi) sacc[mi] += s[mi];
            }
        }
    }
    const int k = khalf * 8 + kq;
    float* kbase = kvspart + (((long)(sp * 64 + bh) * 16 + k) * 64 + mg * 8) * 32 + dg * 4;
    #pragma unroll
    for (int mi = 0; mi < 8; ++mi)
        *reinterpret_cast<float4*>(kbase + mi * 32) =
            make_float4(acc[mi][0], acc[mi][1], acc[mi][2], acc[mi][3]);
    if (dg == 0) {
        float* sb = ksumpart + ((long)(sp * 64 + bh) * 16 + k) * 64 + mg * 8;
        #pragma unroll
        for (int mi = 0; mi < 8; ++mi) sb[mi] = sacc[mi];
    }
}

// ---- 5b. reduce split partials ----
__global__ __launch_bounds__(256) void kvsreduce_kernel(
    const float* __restrict__ kvspart, const float* __restrict__ ksumpart,
    float* __restrict__ kvs, float* __restrict__ ksum)
{
    constexpr int NKVS4 = 2097152 / 4;
    constexpr int NKS = 65536;
    const int idx = blockIdx.x * 256 + threadIdx.x;
    if (idx < NKVS4) {
        const float4* p = reinterpret_cast<const float4*>(kvspart) + idx;
        float4 a = p[0], b4 = p[NKVS4], c = p[2 * NKVS4];
        reinterpret_cast<float4*>(kvs)[idx] =
            make_float4(a.x + b4.x + c.x, a.y + b4.y + c.y,
                        a.z + b4.z + c.z, a.w + b4.w + c.w);
    } else if (idx < NKVS4 + NKS) {
        int j = idx - NKVS4;
        ksum[j] = ksumpart[j] + ksumpart[NKS + j] + ksumpart[2 * NKS + j];
    }
}

// ---- 6. z = LN(mean_k (qp.kvs)*invden) — LDS padded: bank-conflict-free ----
__global__ __launch_bounds__(320) void z_kernel(
    const float* __restrict__ qp, const float* __restrict__ kvs,
    const float* __restrict__ ksum, const float* __restrict__ ln_g,
    const float* __restrict__ ln_b, float* __restrict__ z)
{
    __shared__ float qps[80][65];     // pad 65: qps[r][m] bank=(r+m)%32
    __shared__ float kvss[2048];      // float4-read, broadcast-clean
    __shared__ float ksums[16][65];   // pad 65: ksums[kk][m] bank=(kk+m)%32
    __shared__ float invden[80][17];  // pad 17
    const int bi = blockIdx.x;        // 640
    const int bh = bi / 10;
    const int b = bh >> 3, h = bh & 7;
    const int l0 = (bi % 10) * 80;
    const int t = threadIdx.x;        // 320
    for (int j = t; j < 80 * 64; j += 320) {
        int ll = j >> 6;
        qps[ll][j & 63] = qp[((b * L + l0 + ll) * 8 + h) * 64 + (j & 63)];
    }
    for (int j = t; j < 16 * 64; j += 320)
        ksums[j >> 6][j & 63] = ksum[(long)bh * 1024 + j];
    __syncthreads();
    for (int j = t; j < 80 * 16; j += 320) {
        int ll = j >> 4, kk = j & 15;
        float s = 0.f;
        #pragma unroll 8
        for (int m = 0; m < 64; ++m) s += qps[ll][m] * ksums[kk][m];
        invden[ll][kk] = 1.0f / (s + 1e-8f);
    }
    const int lg = t >> 3;
    const int dg = t & 7;
    const int r0 = lg * 2, r1 = r0 + 1;
    float acc0[4] = {0, 0, 0, 0}, acc1[4] = {0, 0, 0, 0};
    for (int kk = 0; kk < 16; ++kk) {
        __syncthreads();
        const float4* src = reinterpret_cast<const float4*>(kvs + ((long)bh * 16 + kk) * 2048);
        for (int j = t; j < 512; j += 320)
            reinterpret_cast<float4*>(kvss)[j] = src[j];
        __syncthreads();
        float n0[4] = {0, 0, 0, 0}, n1[4] = {0, 0, 0, 0};
        #pragma unroll 4
        for (int m = 0; m < 64; ++m) {
            float4 k4 = *reinterpret_cast<const float4*>(&kvss[m * 32 + dg * 4]);
            float q0 = qps[r0][m], q1 = qps[r1][m];
            n0[0] += q0 * k4.x; n0[1] += q0 * k4.y; n0[2] += q0 * k4.z; n0[3] += q0 * k4.w;
            n1[0] += q1 * k4.x; n1[1] += q1 * k4.y; n1[2] += q1 * k4.z; n1[3] += q1 * k4.w;
        }
        float i0 = invden[r0][kk], i1 = invden[r1][kk];
        #pragma unroll
        for (int j = 0; j < 4; ++j) { acc0[j] += n0[j] * i0; acc1[j] += n1[j] * i1; }
    }
    const float4 g4 = reinterpret_cast<const float4*>(ln_g)[dg];
    const float4 b4 = reinterpret_cast<const float4*>(ln_b)[dg];
    #pragma unroll
    for (int ri = 0; ri < 2; ++ri) {
        float* a = ri ? acc1 : acc0;
        float zv[4];
        float s1 = 0.f, s2 = 0.f;
        #pragma unroll
        for (int j = 0; j < 4; ++j) {
            zv[j] = a[j] * (1.0f / 16.0f);
            s1 += zv[j]; s2 += zv[j] * zv[j];
        }
        #pragma unroll
        for (int off = 1; off < 8; off <<= 1) {
            s1 += __shfl_xor(s1, off);
            s2 += __shfl_xor(s2, off);
        }
        float mu = s1 * (1.0f / 32.0f);
        float var = s2 * (1.0f / 32.0f) - mu * mu;
        float rs = rsqrtf(var + 1e-5f);
        float4 o;
        o.x = (zv[0] - mu) * rs * g4.x + b4.x;
        o.y = (zv[1] - mu) * rs * g4.y + b4.y;
        o.z = (zv[2] - mu) * rs * g4.z + b4.z;
        o.w = (zv[3] - mu) * rs * g4.w + b4.w;
        const int r = ri ? r1 : r0;
        *reinterpret_cast<float4*>(&z[(b * L + l0 + r) * 256 + h * 32 + dg * 4]) = o;
    }
}

// ---- 7. fused + row L1-normalize ----
__global__ __launch_bounds__(128) void fused_kernel(
    const float* __restrict__ adj, const float* __restrict__ wsm,
    float* __restrict__ fusedn)
{
    __shared__ float part[2];
    const int bi = blockIdx.x;
    const int b = bi / 800;
    const int p = (bi / 100) & 7;
    const int i = bi % 100;
    const int t = threadIdx.x;
    float f = 0.f;
    if (t < 100) {
        #pragma unroll
        for (int pl = 0; pl < 8; ++pl)
            f += adj[((long)(b * 64 + p * 8 + pl)) * NN + i * 100 + t] * wsm[(b * 8 + p) * 8 + pl];
    }
    float a = fabsf(f);
    #pragma unroll
    for (int off = 1; off < 64; off <<= 1) a += __shfl_xor(a, off);
    if ((t & 63) == 0) part[t >> 6] = a;
    __syncthreads();
    float denom = fmaxf(part[0] + part[1], 1e-12f);
    if (t < 100) fusedn[(long)bi * 100 + t] = f / denom;
}

// ---- 8. z += block-diag(fusedn) @ v ----
__global__ __launch_bounds__(256) void bias_kernel(
    const float* __restrict__ fusedn, const float* __restrict__ vb,
    float* __restrict__ z)
{
    __shared__ float fs[10 * 100];
    const int bi = blockIdx.x;
    const int bp = bi / 10;
    const int b = bp >> 3, p = bp & 7;
    const int i0 = (bi % 10) * 10;
    const int t = threadIdx.x;
    for (int j = t; j < 1000; j += 256)
        fs[j] = fusedn[(long)bp * 10000 + i0 * 100 + j];
    __syncthreads();
    float acc[10];
    #pragma unroll
    for (int r = 0; r < 10; ++r) acc[r] = 0.f;
    for (int j = 0; j < 100; ++j) {
        float vj = vb[(b * 800 + p * 100 + j) * 256 + t];
        #pragma unroll
        for (int r = 0; r < 10; ++r)
            acc[r] += fs[r * 100 + j] * vj;
    }
    for (int r = 0; r < 10; ++r)
        z[(b * 800 + p * 100 + i0 + r) * 256 + t] += acc[r];
}

// ---- 9. out = zb @ Wo^T + bo ----
__global__ __launch_bounds__(256) void out_kernel(
    const float* __restrict__ z, const float* __restrict__ Wo,
    const float* __restrict__ bo, float* __restrict__ out)
{
    __shared__ float zs[8][256];
    const int row0 = blockIdx.x * 8;
    const int t = threadIdx.x;
    for (int r = 0; r < 8; ++r) zs[r][t] = z[(row0 + r) * 256 + t];
    __syncthreads();
    float acc[8];
    #pragma unroll
    for (int r = 0; r < 8; ++r) acc[r] = 0.f;
    const float4* w4 = reinterpret_cast<const float4*>(Wo) + t * 64;
    for (int kk = 0; kk < 64; ++kk) {
        float4 wv = w4[kk];
        #pragma unroll
        for (int r = 0; r < 8; ++r) {
            const float* zr = &zs[r][kk * 4];
            acc[r] += zr[0] * wv.x + zr[1] * wv.y + zr[2] * wv.z + zr[3] * wv.w;
        }
    }
    float bb = bo[t];
    for (int r = 0; r < 8; ++r) out[(row0 + r) * 256 + t] = acc[r] + bb;
}

extern "C" void kernel_launch(void* const* d_in, const int* in_sizes, int n_in,
                              void* d_out, int out_size, void* d_ws, size_t ws_size,
                              hipStream_t stream) {
    const float* x     = (const float*)d_in[0];
    const float* adj   = (const float*)d_in[1];
    const float* Wq_w  = (const float*)d_in[2];
    const float* Wq_b  = (const float*)d_in[3];
    const float* Wk_w  = (const float*)d_in[4];
    const float* Wk_b  = (const float*)d_in[5];
    const float* Wv_w  = (const float*)d_in[6];
    const float* Wv_b  = (const float*)d_in[7];
    const float* Wo_w  = (const float*)d_in[8];
    const float* Wo_b  = (const float*)d_in[9];
    const float* ln_g  = (const float*)d_in[10];
    const float* ln_b  = (const float*)d_in[11];
    const float* fc_w  = (const float*)d_in[12];
    const float* fc_b  = (const float*)d_in[13];
    const float* out_w = (const float*)d_in[14];
    const float* out_b = (const float*)d_in[15];
    const float* proj  = (const float*)d_in[16];
    const float* gum   = (const float*)d_in[17];
    float* out = (float*)d_out;

    // ---- workspace layout (float units) ----
    // Overlay region [0, 6,488,064) time-shared by disjoint-lifetime tenants:
    //  t1 (convert->wsm):   adjb 2,621,440 | fcwb 655,360 | h1part 524,288
    //  t2 (qkv->phiqk):     qbuf 1,638,400 | kbuf 1,638,400
    //  t3 (kvs->kvsreduce): kvspart 6,291,456 | ksumpart 196,608
    //  t4 (z->out):         zbuf 1,638,400 | fusedn 640,000
    float* ws = (float*)d_ws;
    float* ovl = ws;
    unsigned short* adjb = (unsigned short*)ovl;              // 512*10240 bf16
    unsigned short* fcwb = (unsigned short*)(ovl + 2621440);  // 128*10240 bf16
    float* h1part  = ovl + 3276800;     // 524,288
    float* qbuf    = ovl;               // 1,638,400
    float* kbuf    = ovl + 1638400;     // 1,638,400
    float* kvspart = ovl;               // 6,291,456
    float* ksumpart= ovl + 6291456;     // 196,608
    float* zbuf    = ovl;               // 1,638,400
    float* fusedn  = ovl + 1638400;     // 640,000
    float* after   = ws + 6488064;
    float* vbuf    = after;             // 1,638,400
    float* qp      = vbuf + 1638400;    // 3,276,800
    float* kp      = qp + 3276800;      // 3,276,800 (raw dd for keys)
    float* diagk   = kp + 3276800;      // 51,200
    float* kvs     = diagk + 51200;     // 2,097,152
    float* ksum    = kvs + 2097152;     // 65,536
    float* wsm     = ksum + 65536;      // 512
    float* partmax = wsm + 512;         // 1,600
    float* kmax    = partmax + 1600;    // 64

    convert_kernel<<<dim3(40, 640), 256, 0, stream>>>(adj, fc_w, adjb, fcwb);
    adjfc_mfma_kernel<<<512, 256, 0, stream>>>(adjb, fcwb, h1part);
    wsm_kernel<<<64, 128, 0, stream>>>(h1part, fc_b, out_w, out_b, wsm);

    qkv_kernel<<<1200, 256, 0, stream>>>(x, Wq_w, Wq_b, Wk_w, Wk_b, Wv_w, Wv_b,
                                         qbuf, kbuf, vbuf);
    phiqk_kernel<<<3200, 256, 0, stream>>>(qbuf, kbuf, proj, qp, kp, diagk, partmax);
    kmax_kernel<<<64, 64, 0, stream>>>(partmax, kmax);
    kvs_kernel<<<384, 512, 0, stream>>>(kp, diagk, kmax, vbuf, gum, kvspart, ksumpart);
    kvsreduce_kernel<<<2304, 256, 0, stream>>>(kvspart, ksumpart, kvs, ksum);
    z_kernel<<<640, 320, 0, stream>>>(qp, kvs, ksum, ln_g, ln_b, zbuf);
    fused_kernel<<<6400, 128, 0, stream>>>(adj, wsm, fusedn);
    bias_kernel<<<640, 256, 0, stream>>>(fusedn, vbuf, zbuf);
    out_kernel<<<800, 256, 0, stream>>>(zbuf, Wo_w, Wo_b, out);
}

// Round 7
// 453.508 us; speedup vs baseline: 3.7795x; 1.1751x over previous
//
#include <hip/hip_runtime.h>
#include <cstdint>

// ---- static config ----
constexpr int B = 8, P = 8, N = 100, D = 256, H = 8, DK = 32, M = 64, KG = 16;
constexpr int L = P * N;      // 800
constexpr int NN = N * N;     // 10000
constexpr float PHI_SCALE = 0.8408964152537145f;  // (1/sqrt(0.25)) * 32^-0.25
constexpr float MINV = 0.125f;                    // 64^-0.5
constexpr int ADJ_SPLIT = 8;                      // split-K for adjfc MFMA GEMM
constexpr int KPAD = 10240;                       // 10000 padded to 8*1280 (40*32)

typedef __attribute__((ext_vector_type(8))) short short8v;  // 8 bf16
typedef __attribute__((ext_vector_type(4))) float f32x4;
typedef __attribute__((ext_vector_type(4))) unsigned short us4;

__device__ __forceinline__ unsigned short f2b(float f) {
    unsigned u = __float_as_uint(f);
    unsigned r = 0x7fffu + ((u >> 16) & 1u);
    return (unsigned short)((u + r) >> 16);
}

// ---- 0a. convert adj & fc_w to bf16, K-padded to 10240 ----
__global__ __launch_bounds__(256) void convert_kernel(
    const float* __restrict__ adj, const float* __restrict__ fcw,
    unsigned short* __restrict__ adjb, unsigned short* __restrict__ fcwb)
{
    const int col = blockIdx.x * 256 + threadIdx.x;   // 0..10239
    const int row = blockIdx.y;                       // 0..639
    if (row < 512) {
        float v = (col < NN) ? adj[(long)row * NN + col] : 0.f;
        adjb[(long)row * KPAD + col] = f2b(v);
    } else {
        const int r = row - 512;
        float v = (col < NN) ? fcw[(long)r * NN + col] : 0.f;
        fcwb[(long)r * KPAD + col] = f2b(v);
    }
}

// ---- 0b. convert x, Wq|Wk|Wv (concat), Wo to bf16 ----
__global__ __launch_bounds__(256) void convert_xw_kernel(
    const float* __restrict__ x, const float* __restrict__ Wq,
    const float* __restrict__ Wk, const float* __restrict__ Wv,
    const float* __restrict__ Wo,
    unsigned short* __restrict__ xb, unsigned short* __restrict__ wqkvb,
    unsigned short* __restrict__ wob)
{
    const int j = blockIdx.x * 256 + threadIdx.x;     // 0..1,900,543
    if (j < 1638400) {
        xb[j] = f2b(x[j]);
    } else if (j < 1703936) {
        wqkvb[j - 1638400] = f2b(Wq[j - 1638400]);
    } else if (j < 1769472) {
        wqkvb[j - 1638400] = f2b(Wk[j - 1703936]);
    } else if (j < 1835008) {
        wqkvb[j - 1638400] = f2b(Wv[j - 1769472]);
    } else {
        wob[j - 1835008] = f2b(Wo[j - 1835008]);
    }
}

// ---- 1. adjfc via MFMA: h1part[sp][r][c] partials of flat@fcw^T ----
__global__ __launch_bounds__(256) void adjfc_mfma_kernel(
    const unsigned short* __restrict__ adjb, const unsigned short* __restrict__ fcwb,
    float* __restrict__ h1part)
{
    const int task = blockIdx.x * 4 + (threadIdx.x >> 6);  // 2048 tasks
    const int kt = task & 7;
    const int nt = (task >> 3) & 7;
    const int mt = task >> 6;            // 0..31
    const int lane = threadIdx.x & 63;
    const int row = lane & 15;
    const int ko = (lane >> 4) * 8;
    const unsigned short* pa = adjb + (long)(mt * 16 + row) * KPAD + kt * 1280 + ko;
    const unsigned short* pb = fcwb + (long)(nt * 16 + row) * KPAD + kt * 1280 + ko;
    f32x4 acc = {0.f, 0.f, 0.f, 0.f};
    #pragma unroll 4
    for (int s = 0; s < 40; ++s) {
        short8v a = *reinterpret_cast<const short8v*>(pa);
        short8v b = *reinterpret_cast<const short8v*>(pb);
        acc = __builtin_amdgcn_mfma_f32_16x16x32_bf16(a, b, acc, 0, 0, 0);
        pa += 32; pb += 32;
    }
    const int c = nt * 16 + (lane & 15);
    const int rbase = mt * 16 + (lane >> 4) * 4;
    #pragma unroll
    for (int j = 0; j < 4; ++j) {
        int r = rbase + j;
        h1part[((long)kt * 512 + r) * 128 + c] = acc[j];
    }
}

// ---- 2. w = softmax over patch_len; absorbs split-reduce + bias + relu ----
__global__ __launch_bounds__(128) void wsm_kernel(
    const float* __restrict__ h1part, const float* __restrict__ fcb,
    const float* __restrict__ ow, const float* __restrict__ ob,
    float* __restrict__ wsm)
{
    __shared__ float part[8][2];
    const int bp = blockIdx.x;
    const int t = threadIdx.x;   // 128
    float owv = ow[t], bb = fcb[t];
    for (int pl = 0; pl < 8; ++pl) {
        float h = 0.f;
        for (int s = 0; s < ADJ_SPLIT; ++s)
            h += h1part[((long)s * 512 + bp * 8 + pl) * 128 + t];
        float v = fmaxf(h + bb, 0.f) * owv;
        #pragma unroll
        for (int off = 1; off < 64; off <<= 1) v += __shfl_xor(v, off);
        if ((t & 63) == 0) part[pl][t >> 6] = v;
    }
    __syncthreads();
    if (t == 0) {
        float lg[8], mx = -1e30f;
        for (int pl = 0; pl < 8; ++pl) {
            lg[pl] = part[pl][0] + part[pl][1] + ob[0];
            mx = fmaxf(mx, lg[pl]);
        }
        float s = 0.f;
        for (int pl = 0; pl < 8; ++pl) { lg[pl] = expf(lg[pl] - mx); s += lg[pl]; }
        for (int pl = 0; pl < 8; ++pl) wsm[bp * 8 + pl] = lg[pl] / s;
    }
}

// ---- 3. qkv via MFMA: [6400x256] @ [256x768] + bias ----
__global__ __launch_bounds__(256) void qkv_mfma_kernel(
    const unsigned short* __restrict__ xb, const unsigned short* __restrict__ wqkvb,
    const float* __restrict__ bq, const float* __restrict__ bk,
    const float* __restrict__ bv,
    float* __restrict__ q, float* __restrict__ k, float* __restrict__ v)
{
    const int task = blockIdx.x * 4 + (threadIdx.x >> 6);  // 19200 tasks
    const int nt = task % 48;
    const int mt = task / 48;            // 0..399
    const int lane = threadIdx.x & 63;
    const int row = lane & 15;
    const int ko = (lane >> 4) * 8;
    const unsigned short* pa = xb + (long)(mt * 16 + row) * 256 + ko;
    const unsigned short* pb = wqkvb + (long)(nt * 16 + row) * 256 + ko;
    f32x4 acc = {0.f, 0.f, 0.f, 0.f};
    #pragma unroll
    for (int s = 0; s < 8; ++s) {
        short8v a = *reinterpret_cast<const short8v*>(pa + s * 32);
        short8v b = *reinterpret_cast<const short8v*>(pb + s * 32);
        acc = __builtin_amdgcn_mfma_f32_16x16x32_bf16(a, b, acc, 0, 0, 0);
    }
    const int matid = nt >> 4;           // 0=q, 1=k, 2=v
    const int col = (nt & 15) * 16 + (lane & 15);
    float* outp = (matid == 0) ? q : ((matid == 1) ? k : v);
    const float* bp = (matid == 0) ? bq : ((matid == 1) ? bk : bv);
    const float bias = bp[col];
    const int rbase = mt * 16 + (lane >> 4) * 4;
    #pragma unroll
    for (int j = 0; j < 4; ++j)
        outp[(long)(rbase + j) * 256 + col] = acc[j] + bias;
}

// ---- 4. phi(q) and phi(k) pass1 in one kernel ----
__global__ __launch_bounds__(256) void phiqk_kernel(
    const float* __restrict__ qb, const float* __restrict__ kb,
    const float* __restrict__ proj,
    float* __restrict__ qp, float* __restrict__ ddout,
    float* __restrict__ diagout, float* __restrict__ partmax)
{
    __shared__ float ps[64 * 33];
    __shared__ float wmax[4];
    const int t = threadIdx.x;
    for (int j = t; j < 2048; j += 256) ps[(j >> 5) * 33 + (j & 31)] = proj[j];
    __syncthreads();
    const int bi = blockIdx.x;            // 3200: [0,1600) q, [1600,3200) k
    const bool isq = bi < 1600;
    const int rb = isq ? bi : bi - 1600;
    const int bh = rb / 25;
    const int b = bh >> 3, h = bh & 7;
    const int lbase = (rb % 25) * 32;
    const int wi = t >> 6;
    const int m = t & 63;
    const float* src = isq ? qb : kb;
    float rmax = -1e30f;
    for (int si = 0; si < 8; ++si) {
        const int l = lbase + si * 4 + wi;
        const float* ptr = src + (b * L + l) * 256 + h * 32;
        float dd = 0.f, diag = 0.f;
        #pragma unroll
        for (int d2 = 0; d2 < 32; ++d2) {
            float xv = ptr[d2] * PHI_SCALE;
            dd += xv * ps[m * 33 + d2];
            diag += xv * xv;
        }
        diag *= 0.5f;
        float s = dd;
        #pragma unroll
        for (int off = 1; off < 64; off <<= 1) s = fmaxf(s, __shfl_xor(s, off));
        const int group = (b * L + l) * 8 + h;
        if (isq) {
            qp[group * 64 + m] = MINV * (expf(dd - diag - s) + 1e-6f);
        } else {
            ddout[group * 64 + m] = dd;
            if (m == 0) diagout[group] = diag;
            rmax = fmaxf(rmax, s);
        }
    }
    if (!isq) {
        if (m == 0) wmax[wi] = rmax;
        __syncthreads();
        if (t == 0)
            partmax[rb] = fmaxf(fmaxf(wmax[0], wmax[1]), fmaxf(wmax[2], wmax[3]));
    }
}

// ---- 4b. reduce 25 partials -> kmax[bh] ----
__global__ __launch_bounds__(64) void kmax_kernel(
    const float* __restrict__ partmax, float* __restrict__ kmax)
{
    const int bh = blockIdx.x;
    const int t = threadIdx.x;
    float s = (t < 25) ? partmax[bh * 25 + t] : -1e30f;
    #pragma unroll
    for (int off = 1; off < 64; off <<= 1) s = fmaxf(s, __shfl_xor(s, off));
    if (t == 0) kmax[bh] = s;
}

// ---- 5. kvs partials (runtime nsplit for occupancy) ----
__global__ __launch_bounds__(512) void kvs_kernel(
    const float* __restrict__ dd, const float* __restrict__ diagk,
    const float* __restrict__ kmax, const float* __restrict__ vb,
    const float* __restrict__ gum,
    float* __restrict__ kvspart, float* __restrict__ ksumpart, int nsplit)
{
    constexpr int TL = 64;
    __shared__ float kps[TL][64];
    __shared__ float vs[TL][32];
    __shared__ float egs[TL][8];
    const int bi = blockIdx.x;            // 64 * nsplit * 2
    const int khalf = bi & 1;
    const int sp = (bi >> 1) % nsplit;
    const int bh = bi / (2 * nsplit);
    const int b = bh >> 3, h = bh & 7;
    const int lstart = sp * L / nsplit;
    const int lend = (sp + 1) * L / nsplit;
    const int t = threadIdx.x;
    const int kq = t >> 6;
    const int mg = (t >> 3) & 7;
    const int dg = t & 7;
    const float stab = kmax[bh];
    float acc[8][4];
    #pragma unroll
    for (int i = 0; i < 8; ++i)
        for (int j = 0; j < 4; ++j) acc[i][j] = 0.f;
    float sacc[8] = {0, 0, 0, 0, 0, 0, 0, 0};
    for (int l0 = lstart; l0 < lend; l0 += TL) {
        const int chunk = min(TL, lend - l0);
        __syncthreads();
        for (int j = t; j < chunk * 64; j += 512) {
            int ll = j >> 6, m = j & 63;
            int g = (b * L + l0 + ll) * 8 + h;
            kps[ll][m] = MINV * (expf(dd[g * 64 + m] - diagk[g] - stab) + 1e-6f);
        }
        for (int j = t; j < chunk * 32; j += 512) {
            int ll = j >> 5;
            vs[ll][j & 31] = vb[(b * L + l0 + ll) * 256 + h * 32 + (j & 31)];
        }
        for (int j = t; j < chunk * 8; j += 512) {
            int ll = j >> 3;
            egs[ll][j & 7] = expf(gum[((b * L + l0 + ll) * 8 + h) * 16 + khalf * 8 + (j & 7)]);
        }
        __syncthreads();
        #pragma unroll 2
        for (int ll = 0; ll < chunk; ++ll) {
            float egv = egs[ll][kq];
            const float4* kr = reinterpret_cast<const float4*>(&kps[ll][mg * 8]);
            float4 ka = kr[0], kb4 = kr[1];
            float4 v4 = *reinterpret_cast<const float4*>(&vs[ll][dg * 4]);
            float s[8];
            s[0] = ka.x * egv;  s[1] = ka.y * egv;  s[2] = ka.z * egv;  s[3] = ka.w * egv;
            s[4] = kb4.x * egv; s[5] = kb4.y * egv; s[6] = kb4.z * egv; s[7] = kb4.w * egv;
            #pragma unroll
            for (int mi = 0; mi < 8; ++mi) {
                acc[mi][0] += s[mi] * v4.x;
                acc[mi][1] += s[mi] * v4.y;
                acc[mi][2] += s[mi] * v4.z;
                acc[mi][3] += s[mi] * v4.w;
            }
            if (dg == 0) {
                #pragma unroll
                for (int mi = 0; mi < 8; ++mi) sacc[mi] += s[mi];
            }
        }
    }
    const int k = khalf * 8 + kq;
    float* kbase = kvspart + (((long)(sp * 64 + bh) * 16 + k) * 64 + mg * 8) * 32 + dg * 4;
    #pragma unroll
    for (int mi = 0; mi < 8; ++mi)
        *reinterpret_cast<float4*>(kbase + mi * 32) =
            make_float4(acc[mi][0], acc[mi][1], acc[mi][2], acc[mi][3]);
    if (dg == 0) {
        float* sb = ksumpart + ((long)(sp * 64 + bh) * 16 + k) * 64 + mg * 8;
        #pragma unroll
        for (int mi = 0; mi < 8; ++mi) sb[mi] = sacc[mi];
    }
}

// ---- 5b. reduce split partials ----
__global__ __launch_bounds__(256) void kvsreduce_kernel(
    const float* __restrict__ kvspart, const float* __restrict__ ksumpart,
    float* __restrict__ kvs, float* __restrict__ ksum, int nsplit)
{
    constexpr int NKVS4 = 2097152 / 4;
    constexpr int NKS = 65536;
    const int idx = blockIdx.x * 256 + threadIdx.x;
    if (idx < NKVS4) {
        const float4* p = reinterpret_cast<const float4*>(kvspart) + idx;
        float4 a = p[0];
        for (int s = 1; s < nsplit; ++s) {
            float4 b4 = p[(long)s * NKVS4];
            a.x += b4.x; a.y += b4.y; a.z += b4.z; a.w += b4.w;
        }
        reinterpret_cast<float4*>(kvs)[idx] = a;
    } else if (idx < NKVS4 + NKS) {
        int j = idx - NKVS4;
        float s = ksumpart[j];
        for (int sp = 1; sp < nsplit; ++sp) s += ksumpart[(long)sp * NKS + j];
        ksum[j] = s;
    }
}

// ---- 6. z = LN(mean_k (qp.kvs)*invden) — padded LDS, conflict-free ----
__global__ __launch_bounds__(320) void z_kernel(
    const float* __restrict__ qp, const float* __restrict__ kvs,
    const float* __restrict__ ksum, const float* __restrict__ ln_g,
    const float* __restrict__ ln_b, float* __restrict__ z)
{
    __shared__ float qps[80][65];
    __shared__ float kvss[2048];
    __shared__ float ksums[16][65];
    __shared__ float invden[80][17];
    const int bi = blockIdx.x;        // 640
    const int bh = bi / 10;
    const int b = bh >> 3, h = bh & 7;
    const int l0 = (bi % 10) * 80;
    const int t = threadIdx.x;        // 320
    for (int j = t; j < 80 * 64; j += 320) {
        int ll = j >> 6;
        qps[ll][j & 63] = qp[((b * L + l0 + ll) * 8 + h) * 64 + (j & 63)];
    }
    for (int j = t; j < 16 * 64; j += 320)
        ksums[j >> 6][j & 63] = ksum[(long)bh * 1024 + j];
    __syncthreads();
    for (int j = t; j < 80 * 16; j += 320) {
        int ll = j >> 4, kk = j & 15;
        float s = 0.f;
        #pragma unroll 8
        for (int m = 0; m < 64; ++m) s += qps[ll][m] * ksums[kk][m];
        invden[ll][kk] = 1.0f / (s + 1e-8f);
    }
    const int lg = t >> 3;
    const int dg = t & 7;
    const int r0 = lg * 2, r1 = r0 + 1;
    float acc0[4] = {0, 0, 0, 0}, acc1[4] = {0, 0, 0, 0};
    for (int kk = 0; kk < 16; ++kk) {
        __syncthreads();
        const float4* src = reinterpret_cast<const float4*>(kvs + ((long)bh * 16 + kk) * 2048);
        for (int j = t; j < 512; j += 320)
            reinterpret_cast<float4*>(kvss)[j] = src[j];
        __syncthreads();
        float n0[4] = {0, 0, 0, 0}, n1[4] = {0, 0, 0, 0};
        #pragma unroll 4
        for (int m = 0; m < 64; ++m) {
            float4 k4 = *reinterpret_cast<const float4*>(&kvss[m * 32 + dg * 4]);
            float q0 = qps[r0][m], q1 = qps[r1][m];
            n0[0] += q0 * k4.x; n0[1] += q0 * k4.y; n0[2] += q0 * k4.z; n0[3] += q0 * k4.w;
            n1[0] += q1 * k4.x; n1[1] += q1 * k4.y; n1[2] += q1 * k4.z; n1[3] += q1 * k4.w;
        }
        float i0 = invden[r0][kk], i1 = invden[r1][kk];
        #pragma unroll
        for (int j = 0; j < 4; ++j) { acc0[j] += n0[j] * i0; acc1[j] += n1[j] * i1; }
    }
    const float4 g4 = reinterpret_cast<const float4*>(ln_g)[dg];
    const float4 b4 = reinterpret_cast<const float4*>(ln_b)[dg];
    #pragma unroll
    for (int ri = 0; ri < 2; ++ri) {
        float* a = ri ? acc1 : acc0;
        float zv[4];
        float s1 = 0.f, s2 = 0.f;
        #pragma unroll
        for (int j = 0; j < 4; ++j) {
            zv[j] = a[j] * (1.0f / 16.0f);
            s1 += zv[j]; s2 += zv[j] * zv[j];
        }
        #pragma unroll
        for (int off = 1; off < 8; off <<= 1) {
            s1 += __shfl_xor(s1, off);
            s2 += __shfl_xor(s2, off);
        }
        float mu = s1 * (1.0f / 32.0f);
        float var = s2 * (1.0f / 32.0f) - mu * mu;
        float rs = rsqrtf(var + 1e-5f);
        float4 o;
        o.x = (zv[0] - mu) * rs * g4.x + b4.x;
        o.y = (zv[1] - mu) * rs * g4.y + b4.y;
        o.z = (zv[2] - mu) * rs * g4.z + b4.z;
        o.w = (zv[3] - mu) * rs * g4.w + b4.w;
        const int r = ri ? r1 : r0;
        *reinterpret_cast<float4*>(&z[(b * L + l0 + r) * 256 + h * 32 + dg * 4]) = o;
    }
}

// ---- 7. fused + row L1-normalize ----
__global__ __launch_bounds__(128) void fused_kernel(
    const float* __restrict__ adj, const float* __restrict__ wsm,
    float* __restrict__ fusedn)
{
    __shared__ float part[2];
    const int bi = blockIdx.x;
    const int b = bi / 800;
    const int p = (bi / 100) & 7;
    const int i = bi % 100;
    const int t = threadIdx.x;
    float f = 0.f;
    if (t < 100) {
        #pragma unroll
        for (int pl = 0; pl < 8; ++pl)
            f += adj[((long)(b * 64 + p * 8 + pl)) * NN + i * 100 + t] * wsm[(b * 8 + p) * 8 + pl];
    }
    float a = fabsf(f);
    #pragma unroll
    for (int off = 1; off < 64; off <<= 1) a += __shfl_xor(a, off);
    if ((t & 63) == 0) part[t >> 6] = a;
    __syncthreads();
    float denom = fmaxf(part[0] + part[1], 1e-12f);
    if (t < 100) fusedn[(long)bi * 100 + t] = f / denom;
}

// ---- 8. z += block-diag(fusedn) @ v ----
__global__ __launch_bounds__(256) void bias_kernel(
    const float* __restrict__ fusedn, const float* __restrict__ vb,
    float* __restrict__ z)
{
    __shared__ float fs[10 * 100];
    const int bi = blockIdx.x;
    const int bp = bi / 10;
    const int b = bp >> 3, p = bp & 7;
    const int i0 = (bi % 10) * 10;
    const int t = threadIdx.x;
    for (int j = t; j < 1000; j += 256)
        fs[j] = fusedn[(long)bp * 10000 + i0 * 100 + j];
    __syncthreads();
    float acc[10];
    #pragma unroll
    for (int r = 0; r < 10; ++r) acc[r] = 0.f;
    for (int j = 0; j < 100; ++j) {
        float vj = vb[(b * 800 + p * 100 + j) * 256 + t];
        #pragma unroll
        for (int r = 0; r < 10; ++r)
            acc[r] += fs[r * 100 + j] * vj;
    }
    for (int r = 0; r < 10; ++r)
        z[(b * 800 + p * 100 + i0 + r) * 256 + t] += acc[r];
}

// ---- 9a. convert z to bf16 ----
__global__ __launch_bounds__(256) void convert_z_kernel(
    const float* __restrict__ z, unsigned short* __restrict__ zb)
{
    const int i = (blockIdx.x * 256 + threadIdx.x) * 4;   // 1600 blocks
    float4 v = *reinterpret_cast<const float4*>(z + i);
    us4 o = { f2b(v.x), f2b(v.y), f2b(v.z), f2b(v.w) };
    *reinterpret_cast<us4*>(zb + i) = o;
}

// ---- 9b. out via MFMA: [6400x256] @ [256x256] + bias ----
__global__ __launch_bounds__(256) void out_mfma_kernel(
    const unsigned short* __restrict__ zb, const unsigned short* __restrict__ wob,
    const float* __restrict__ bo, float* __restrict__ out)
{
    const int task = blockIdx.x * 4 + (threadIdx.x >> 6);  // 6400 tasks
    const int nt = task & 15;
    const int mt = task >> 4;            // 0..399
    const int lane = threadIdx.x & 63;
    const int row = lane & 15;
    const int ko = (lane >> 4) * 8;
    const unsigned short* pa = zb + (long)(mt * 16 + row) * 256 + ko;
    const unsigned short* pb = wob + (long)(nt * 16 + row) * 256 + ko;
    f32x4 acc = {0.f, 0.f, 0.f, 0.f};
    #pragma unroll
    for (int s = 0; s < 8; ++s) {
        short8v a = *reinterpret_cast<const short8v*>(pa + s * 32);
        short8v b = *reinterpret_cast<const short8v*>(pb + s * 32);
        acc = __builtin_amdgcn_mfma_f32_16x16x32_bf16(a, b, acc, 0, 0, 0);
    }
    const int col = nt * 16 + (lane & 15);
    const float bias = bo[col];
    const int rbase = mt * 16 + (lane >> 4) * 4;
    #pragma unroll
    for (int j = 0; j < 4; ++j)
        out[(long)(rbase + j) * 256 + col] = acc[j] + bias;
}

extern "C" void kernel_launch(void* const* d_in, const int* in_sizes, int n_in,
                              void* d_out, int out_size, void* d_ws, size_t ws_size,
                              hipStream_t stream) {
    const float* x     = (const float*)d_in[0];
    const float* adj   = (const float*)d_in[1];
    const float* Wq_w  = (const float*)d_in[2];
    const float* Wq_b  = (const float*)d_in[3];
    const float* Wk_w  = (const float*)d_in[4];
    const float* Wk_b  = (const float*)d_in[5];
    const float* Wv_w  = (const float*)d_in[6];
    const float* Wv_b  = (const float*)d_in[7];
    const float* Wo_w  = (const float*)d_in[8];
    const float* Wo_b  = (const float*)d_in[9];
    const float* ln_g  = (const float*)d_in[10];
    const float* ln_b  = (const float*)d_in[11];
    const float* fc_w  = (const float*)d_in[12];
    const float* fc_b  = (const float*)d_in[13];
    const float* out_w = (const float*)d_in[14];
    const float* out_b = (const float*)d_in[15];
    const float* proj  = (const float*)d_in[16];
    const float* gum   = (const float*)d_in[17];
    float* out = (float*)d_out;

    // ---- workspace layout (float units) ----
    // Overlay region time-shared by disjoint-lifetime tenants:
    //  t1 (convert->wsm):   adjb 2,621,440 | fcwb 327,680 | h1part @3,276,800 (+524,288)
    //  t2 (convxw->phiqk):  qbuf 1,638,400 | kbuf 1,638,400 | xb @3,276,800 (819,200)
    //                       | wqkvb @4,096,000 (98,304)
    //  t3 (kvs->kvsreduce): kvspart nsplit*2,097,152 | ksumpart nsplit*65,536
    //  t4 (z->out):         zbuf 1,638,400 | fusedn 640,000
    float* ws = (float*)d_ws;
    const size_t wsfl = ws_size / sizeof(float);
    constexpr size_t AFTER_NEED = 11260032;
    const int nsplit = (wsfl >= (size_t)6 * 2162688 + AFTER_NEED) ? 6 : 3;
    const size_t OVL = (size_t)nsplit * 2162688;   // >= all other tenants for nsplit>=2

    float* ovl = ws;
    unsigned short* adjb = (unsigned short*)ovl;              // 512*10240 bf16
    unsigned short* fcwb = (unsigned short*)(ovl + 2621440);  // 128*10240 bf16
    float* h1part  = ovl + 3276800;       // 524,288
    float* qbuf    = ovl;                 // 1,638,400
    float* kbuf    = ovl + 1638400;       // 1,638,400
    unsigned short* xb    = (unsigned short*)(ovl + 3276800); // 1,638,400 bf16
    unsigned short* wqkvb = (unsigned short*)(ovl + 4096000); // 196,608 bf16
    float* kvspart = ovl;                 // nsplit * 2,097,152
    float* ksumpart= ovl + (size_t)nsplit * 2097152;  // nsplit * 65,536
    float* zbuf    = ovl;                 // 1,638,400
    float* fusedn  = ovl + 1638400;       // 640,000

    float* after   = ws + OVL;
    float* vbuf    = after;               // 1,638,400
    float* qp      = vbuf + 1638400;      // 3,276,800
    float* kp      = qp + 3276800;        // 3,276,800 (raw dd for keys)
    float* diagk   = kp + 3276800;        // 51,200
    float* kvs     = diagk + 51200;       // 2,097,152
    float* ksum    = kvs + 2097152;       // 65,536
    float* wsm     = ksum + 65536;        // 512
    float* partmax = wsm + 512;           // 1,600
    float* kmax    = partmax + 1600;      // 64
    unsigned short* wob  = (unsigned short*)(kmax + 64);      // 65,536 bf16
    unsigned short* zb16 = (unsigned short*)(kmax + 64 + 32768); // 1,638,400 bf16

    // adj path first so t1 tenants die before qkv
    convert_kernel<<<dim3(40, 640), 256, 0, stream>>>(adj, fc_w, adjb, fcwb);
    adjfc_mfma_kernel<<<512, 256, 0, stream>>>(adjb, fcwb, h1part);
    wsm_kernel<<<64, 128, 0, stream>>>(h1part, fc_b, out_w, out_b, wsm);

    convert_xw_kernel<<<7424, 256, 0, stream>>>(x, Wq_w, Wk_w, Wv_w, Wo_w,
                                                xb, wqkvb, wob);
    qkv_mfma_kernel<<<4800, 256, 0, stream>>>(xb, wqkvb, Wq_b, Wk_b, Wv_b,
                                              qbuf, kbuf, vbuf);
    phiqk_kernel<<<3200, 256, 0, stream>>>(qbuf, kbuf, proj, qp, kp, diagk, partmax);
    kmax_kernel<<<64, 64, 0, stream>>>(partmax, kmax);
    kvs_kernel<<<64 * nsplit * 2, 512, 0, stream>>>(kp, diagk, kmax, vbuf, gum,
                                                    kvspart, ksumpart, nsplit);
    kvsreduce_kernel<<<2304, 256, 0, stream>>>(kvspart, ksumpart, kvs, ksum, nsplit);
    z_kernel<<<640, 320, 0, stream>>>(qp, kvs, ksum, ln_g, ln_b, zbuf);
    fused_kernel<<<6400, 128, 0, stream>>>(adj, wsm, fusedn);
    bias_kernel<<<640, 256, 0, stream>>>(fusedn, vbuf, zbuf);
    convert_z_kernel<<<1600, 256, 0, stream>>>(zbuf, zb16);
    out_mfma_kernel<<<1600, 256, 0, stream>>>(zb16, wob, Wo_b, out);
}